// Round 9
// baseline (647.916 us; speedup 1.0000x reference)
//
#include <hip/hip_runtime.h>
#include <cstdint>
#include <cstddef>

#define NN 8192
#define KFIN 1024
#define KFOUT 256
#define MAXD 192
#define LRALPHA 0.2f

typedef float f32x4 __attribute__((ext_vector_type(4)));

// ---------------------------------------------------------------------------
// Kernel A: dense adj -> CSR neighbor lists (stable ascending-column order via
// 4x ballot on float4 nontemporal loads), degree, s2 = off-diagonal degree.
// ---------------------------------------------------------------------------
__global__ void __launch_bounds__(256) k_build_csr(
    const float* __restrict__ adj, int* __restrict__ nbr,
    int* __restrict__ deg, int* __restrict__ s2v) {
  const int wave = threadIdx.x >> 6;
  const int lane = threadIdx.x & 63;
  const int row = blockIdx.x * 4 + wave;
  const float* arow = adj + (size_t)row * NN;
  int* outp = nbr + (size_t)row * MAXD;
  int count = 0;
  int dflag = 0;
  const unsigned long long below = (1ull << lane) - 1ull;
  for (int c0 = 0; c0 < NN; c0 += 256) {
    const int c = c0 + lane * 4;
    const f32x4 v = __builtin_nontemporal_load(
        reinterpret_cast<const f32x4*>(arow + c));
    const unsigned long long m0 = __ballot(v[0] > 0.0f);
    const unsigned long long m1 = __ballot(v[1] > 0.0f);
    const unsigned long long m2 = __ballot(v[2] > 0.0f);
    const unsigned long long m3 = __ballot(v[3] > 0.0f);
    int pos = count + (int)(__popcll(m0 & below) + __popcll(m1 & below) +
                            __popcll(m2 & below) + __popcll(m3 & below));
    if (v[0] > 0.0f) { if (pos < MAXD) outp[pos] = c + 0; ++pos; if (c + 0 == row) dflag = 1; }
    if (v[1] > 0.0f) { if (pos < MAXD) outp[pos] = c + 1; ++pos; if (c + 1 == row) dflag = 1; }
    if (v[2] > 0.0f) { if (pos < MAXD) outp[pos] = c + 2; ++pos; if (c + 2 == row) dflag = 1; }
    if (v[3] > 0.0f) { if (pos < MAXD) outp[pos] = c + 3; ++pos; if (c + 3 == row) dflag = 1; }
    count += (int)(__popcll(m0) + __popcll(m1) + __popcll(m2) + __popcll(m3));
  }
  const int anyd = __any(dflag) ? 1 : 0;
  if (lane == 0) {
    deg[row] = count < MAXD ? count : MAXD;
    s2v[row] = count - anyd;
  }
}

// ---------------------------------------------------------------------------
// Kernel B: Wh = h @ W, f32 tiled GEMM (64x64 tile, 4x4 per thread, BK=16).
// ---------------------------------------------------------------------------
__global__ void __launch_bounds__(256) k_gemm(
    const float* __restrict__ A, const float* __restrict__ B,
    float* __restrict__ C) {
  __shared__ float As[16][65];
  __shared__ float Bs[16][65];
  const int tid = threadIdx.x;
  const int brow = blockIdx.y * 64;
  const int bcol = blockIdx.x * 64;
  const int tx = tid & 15;
  const int ty = tid >> 4;
  float acc[4][4];
#pragma unroll
  for (int i = 0; i < 4; ++i)
#pragma unroll
    for (int j = 0; j < 4; ++j) acc[i][j] = 0.0f;
  const int ar = tid >> 2;
  const int ac = (tid & 3) << 2;
  const int br = tid >> 4;
  const int bc = (tid & 15) << 2;
  for (int k0 = 0; k0 < KFIN; k0 += 16) {
    const float4 av =
        *reinterpret_cast<const float4*>(A + (size_t)(brow + ar) * KFIN + k0 + ac);
    const float4 bv =
        *reinterpret_cast<const float4*>(B + (size_t)(k0 + br) * KFOUT + bcol + bc);
    As[ac + 0][ar] = av.x;
    As[ac + 1][ar] = av.y;
    As[ac + 2][ar] = av.z;
    As[ac + 3][ar] = av.w;
    Bs[br][bc + 0] = bv.x;
    Bs[br][bc + 1] = bv.y;
    Bs[br][bc + 2] = bv.z;
    Bs[br][bc + 3] = bv.w;
    __syncthreads();
#pragma unroll
    for (int kk = 0; kk < 16; ++kk) {
      const float a0 = As[kk][ty * 4 + 0];
      const float a1 = As[kk][ty * 4 + 1];
      const float a2 = As[kk][ty * 4 + 2];
      const float a3 = As[kk][ty * 4 + 3];
      const float b0 = Bs[kk][tx * 4 + 0];
      const float b1 = Bs[kk][tx * 4 + 1];
      const float b2 = Bs[kk][tx * 4 + 2];
      const float b3 = Bs[kk][tx * 4 + 3];
      acc[0][0] += a0 * b0; acc[0][1] += a0 * b1; acc[0][2] += a0 * b2; acc[0][3] += a0 * b3;
      acc[1][0] += a1 * b0; acc[1][1] += a1 * b1; acc[1][2] += a1 * b2; acc[1][3] += a1 * b3;
      acc[2][0] += a2 * b0; acc[2][1] += a2 * b1; acc[2][2] += a2 * b2; acc[2][3] += a2 * b3;
      acc[3][0] += a3 * b0; acc[3][1] += a3 * b1; acc[3][2] += a3 * b2; acc[3][3] += a3 * b3;
    }
    __syncthreads();
  }
#pragma unroll
  for (int i = 0; i < 4; ++i) {
#pragma unroll
    for (int j = 0; j < 4; ++j) {
      C[(size_t)(brow + ty * 4 + i) * KFOUT + bcol + tx * 4 + j] = acc[i][j];
    }
  }
}

// ---------------------------------------------------------------------------
// Kernel C: Wh1 = Wh @ a[:256], Wh2 = Wh @ a[256:], one block per row.
// ---------------------------------------------------------------------------
__global__ void __launch_bounds__(256) k_rowdots(
    const float* __restrict__ Wh, const float* __restrict__ a,
    float* __restrict__ Wh1, float* __restrict__ Wh2) {
  __shared__ float sA[256];
  __shared__ float sB[256];
  const int row = blockIdx.x;
  const int t = threadIdx.x;
  const float w = Wh[(size_t)row * KFOUT + t];
  sA[t] = w * a[t];
  sB[t] = w * a[KFOUT + t];
  __syncthreads();
  for (int s = 128; s > 0; s >>= 1) {
    if (t < s) {
      sA[t] += sA[t + s];
      sB[t] += sB[t + s];
    }
    __syncthreads();
  }
  if (t == 0) {
    Wh1[row] = sA[0];
    Wh2[row] = sB[0];
  }
}

// ---------------------------------------------------------------------------
// Kernel D1: per-row softmax stats (max m, denom Z) over neighbor list.
// ---------------------------------------------------------------------------
__global__ void __launch_bounds__(256) k_stats(
    const int* __restrict__ nbr, const int* __restrict__ deg,
    const float* __restrict__ Wh1, const float* __restrict__ Wh2,
    float* __restrict__ mrow, float* __restrict__ Zrow) {
  const int wave = threadIdx.x >> 6;
  const int lane = threadIdx.x & 63;
  const int row = blockIdx.x * 4 + wave;
  const int d = deg[row];
  const int* cols = nbr + (size_t)row * MAXD;
  const float w1 = Wh1[row];
  float mx = -1e30f;
  for (int t = lane; t < d; t += 64) {
    float e = w1 + Wh2[cols[t]];
    e = e > 0.0f ? e : LRALPHA * e;
    mx = fmaxf(mx, e);
  }
  for (int o = 32; o > 0; o >>= 1) mx = fmaxf(mx, __shfl_xor(mx, o));
  float sum = 0.0f;
  for (int t = lane; t < d; t += 64) {
    float e = w1 + Wh2[cols[t]];
    e = e > 0.0f ? e : LRALPHA * e;
    sum += expf(e - mx);
  }
  for (int o = 32; o > 0; o >>= 1) sum += __shfl_xor(sum, o);
  if (lane == 0) {
    mrow[row] = mx;
    Zrow[row] = (d > 0) ? sum : 1.0f;
  }
}

// ---------------------------------------------------------------------------
// Kernel D2: attention CSR values + packed transpose-edge values + per-row
// column-OCTANT split counts (cols ascending -> octants contiguous).
// qb8[row][m-1] = count(col < m*1024) for m=1..7; qb8[row][7] = d.
// ---------------------------------------------------------------------------
__global__ void __launch_bounds__(256) k_att(
    const int* __restrict__ nbr, const int* __restrict__ deg,
    const float* __restrict__ Wh1, const float* __restrict__ Wh2,
    const float* __restrict__ mrow, const float* __restrict__ Zrow,
    float* __restrict__ att, int2* __restrict__ edgesT,
    short* __restrict__ qb8) {
  const int wave = threadIdx.x >> 6;
  const int lane = threadIdx.x & 63;
  const int row = blockIdx.x * 4 + wave;
  const int d = deg[row];
  const int* cols = nbr + (size_t)row * MAXD;
  const float w1r = Wh1[row];
  const float w2r = Wh2[row];
  const float mr = mrow[row];
  const float invZr = 1.0f / Zrow[row];
  int b[7] = {0, 0, 0, 0, 0, 0, 0};
  for (int t0 = 0; t0 < d; t0 += 64) {
    const int t = t0 + lane;
    const bool act = t < d;
    const int j = act ? cols[t] : 0x7fffffff;
#pragma unroll
    for (int m = 1; m <= 7; ++m)
      b[m - 1] += (int)__popcll(__ballot(act && j < m * 1024));
    if (act) {
      float e = w1r + Wh2[j];
      e = e > 0.0f ? e : LRALPHA * e;
      att[(size_t)row * MAXD + t] = expf(e - mr) * invZr;
      float e2 = Wh1[j] + w2r;
      e2 = e2 > 0.0f ? e2 : LRALPHA * e2;
      const float v = expf(e2 - mrow[j]) / Zrow[j];
      edgesT[(size_t)row * MAXD + t] = make_int2(j, __float_as_int(v));
    }
  }
  if (lane == 0) {
    short* q = qb8 + (size_t)row * 8;
    q[0] = (short)b[0]; q[1] = (short)b[1]; q[2] = (short)b[2]; q[3] = (short)b[3];
    q[4] = (short)b[4]; q[5] = (short)b[5]; q[6] = (short)b[6]; q[7] = (short)d;
  }
}

// ---------------------------------------------------------------------------
// Kernel E: per row i, 512 threads (8 waves), comb row in LDS.
// Octant-partitioned scatter, 16-lane groups, fixed-trip depth-4 pipeline.
// Radix select of the s2-th largest with WAVE-AGGREGATED pass-0 histogram:
// comb values cluster into ~8 exponent bins, so direct LDS atomicAdd
// serializes 4-15 deep per wave-instruction in the shared LDS unit; ballot
// aggregation (leader broadcast + popcount, one atomic per distinct bin)
// moves that cost onto the 4 parallel VALU pipes. Counts are order-
// independent -> deterministic. Passes 1-3 hash mantissa bytes (uniform)
// -> direct atomics stay cheap.
// ---------------------------------------------------------------------------
__global__ void __launch_bounds__(512) k_twostep(
    const int* __restrict__ nbr, const int* __restrict__ deg,
    const int* __restrict__ s2v, const float* __restrict__ att,
    const int2* __restrict__ edgesT, const short* __restrict__ qb8,
    float* __restrict__ out1) {
  __shared__ float comb[NN];
  __shared__ float wvals[MAXD];
  __shared__ int kcols[MAXD];
  __shared__ int kbase[MAXD];
  __shared__ unsigned short packw[8][MAXD];
  __shared__ unsigned int hist[256];
  __shared__ unsigned int shPrefix;
  __shared__ int shRemaining;
  const int tid = threadIdx.x;
  const int wave = tid >> 6;
  const int lane = tid & 63;
  const int row = blockIdx.x;
  const f32x4 z4 = {0.0f, 0.0f, 0.0f, 0.0f};
  for (int j = tid * 4; j < NN; j += 2048)
    *reinterpret_cast<f32x4*>(&comb[j]) = z4;
  const int d = deg[row];
  const int* cols = nbr + (size_t)row * MAXD;
  const float* arow = att + (size_t)row * MAXD;
  for (int t = tid; t < d; t += 512) {
    const int c = cols[t];
    kcols[t] = c;
    kbase[t] = c * MAXD;
    wvals[t] = arow[t];
  }
  for (int tt = tid; tt < d * 8; tt += 512) {
    const int t = tt >> 3;
    const int w = tt & 7;
    const int c = cols[t];
    const int qe = (int)qb8[(size_t)c * 8 + w];
    const int qs = w ? (int)qb8[(size_t)c * 8 + w - 1] : 0;
    packw[w][t] = (unsigned short)(qs | (qe << 8));
  }
  __syncthreads();
  // --- phase A: fixed-trip depth-4 pipelined scatter, 16-lane groups
  {
    const int grp = lane >> 4;   // 0..3
    const int sub = lane & 15;   // 0..15
    const int nsteps = (d + 3) >> 2;
    int2 eA = make_int2(0, 0), eB = make_int2(0, 0);
    int2 eC = make_int2(0, 0), eD = make_int2(0, 0);
    float wA = 0.0f, wB = 0.0f, wC = 0.0f, wD = 0.0f;
    bool pA_ = false, pB_ = false, pC_ = false, pD_ = false;
#define PA_ISSUE(E_, W_, P_, S_)                                       \
    {                                                                   \
      const int t_ = (S_) * 4 + grp;                                    \
      const bool v_ = t_ < d;                                           \
      const unsigned pk_ = v_ ? (unsigned)packw[wave][t_] : 0u;         \
      const int qs_ = (int)(pk_ & 255u);                                \
      const int qe_ = (int)(pk_ >> 8);                                  \
      P_ = v_ && (qs_ + sub) < qe_;                                     \
      W_ = v_ ? wvals[t_] : 0.0f;                                       \
      E_ = make_int2(0, 0);                                             \
      if (P_) E_ = edgesT[(size_t)kbase[t_] + qs_ + sub];               \
    }
    if (nsteps > 0) PA_ISSUE(eA, wA, pA_, 0);
    if (nsteps > 1) PA_ISSUE(eB, wB, pB_, 1);
    if (nsteps > 2) PA_ISSUE(eC, wC, pC_, 2);
    if (nsteps > 3) PA_ISSUE(eD, wD, pD_, 3);
    for (int s = 0; s < nsteps; ++s) {
      const int2 e = eA; const float w = wA; const bool p = pA_;
      eA = eB; wA = wB; pA_ = pB_;
      eB = eC; wB = wC; pB_ = pC_;
      eC = eD; wC = wD; pC_ = pD_;
      if (s + 4 < nsteps) PA_ISSUE(eD, wD, pD_, s + 4);
      if (p) atomicAdd(&comb[e.x], w * __int_as_float(e.y));
    }
#undef PA_ISSUE
  }
  // --- phase B: cleanup for rare octant segments longer than 16
  for (int t0 = 0; t0 < d; t0 += 64) {
    const int t = t0 + lane;
    bool big = false;
    if (t < d) {
      const unsigned pk = (unsigned)packw[wave][t];
      big = ((int)(pk >> 8) - (int)(pk & 255u)) > 16;
    }
    unsigned long long m = __ballot(big);
    while (m) {
      const int tt = t0 + (int)__ffsll((long long)m) - 1;
      m &= m - 1;
      const unsigned pk = (unsigned)packw[wave][tt];
      const int qs = (int)(pk & 255u);
      const int qe = (int)(pk >> 8);
      const float w = wvals[tt];
      const int base = kbase[tt];
      for (int off = qs + 16 + lane; off < qe; off += 64) {
        const int2 e = edgesT[(size_t)base + off];
        atomicAdd(&comb[e.x], w * __int_as_float(e.y));
      }
    }
  }
  // --- add row's own attention values (wave's own octant segment)
  {
    const short* qr = qb8 + (size_t)row * 8;
    const int qlo = wave ? (int)qr[wave - 1] : 0;
    const int qhi = (int)qr[wave];
    for (int t = qlo + lane; t < qhi; t += 64) comb[kcols[t]] += wvals[t];
  }
  __syncthreads();
  if (tid == 0) comb[row] = 0.0f;
  __syncthreads();
  const int kk = s2v[row];
  const size_t obase = (size_t)row * NN;
  if (kk <= 0) {
    for (int j = tid * 4; j < NN; j += 2048)
      __builtin_nontemporal_store(z4, reinterpret_cast<f32x4*>(&out1[obase + j]));
    return;
  }
  // --- radix select: kk-th largest of comb (values >= 0 -> uint order).
  unsigned int prefix = 0u;
  int remaining = kk;
  for (int pass = 0; pass < 4; ++pass) {
    const int shift = 24 - 8 * pass;
    const unsigned int pmask = (pass == 0) ? 0u : (0xFFFFFFFFu << (shift + 8));
    if (tid < 256) hist[tid] = 0u;
    __syncthreads();
    if (pass == 0) {
      // wave-aggregated histogram: one atomic per distinct bin per instr
      for (int j = tid * 4; j < NN; j += 2048) {
        const f32x4 cv = *reinterpret_cast<const f32x4*>(&comb[j]);
#pragma unroll
        for (int q = 0; q < 4; ++q) {
          const unsigned int u = __float_as_uint(cv[q]);
          const bool act = (u != 0u);
          const unsigned int bin = u >> 24;
          unsigned long long mask = __ballot(act);
          while (mask) {
            const int leader = (int)__ffsll((long long)mask) - 1;
            const unsigned int lbin = __shfl(bin, leader);
            const unsigned long long same = __ballot(act && bin == lbin);
            if (lane == leader)
              atomicAdd(&hist[lbin], (unsigned int)__popcll(same));
            mask &= ~same;
          }
        }
      }
    } else {
      for (int j = tid * 4; j < NN; j += 2048) {
        const f32x4 cv = *reinterpret_cast<const f32x4*>(&comb[j]);
#pragma unroll
        for (int q = 0; q < 4; ++q) {
          const unsigned int u = __float_as_uint(cv[q]);
          if (u != 0u && (u & pmask) == prefix)
            atomicAdd(&hist[(u >> shift) & 255u], 1u);
        }
      }
    }
    __syncthreads();
    if (tid < 64) {
      const int bHi = 255 - 4 * lane;  // lane 0 owns highest bins
      const unsigned int c0 = hist[bHi];
      const unsigned int c1 = hist[bHi - 1];
      const unsigned int c2 = hist[bHi - 2];
      const unsigned int c3 = hist[bHi - 3];
      const unsigned int gs = c0 + c1 + c2 + c3;
      unsigned int run2 = gs;
      for (int o = 1; o < 64; o <<= 1) {
        const unsigned int tt = __shfl_up(run2, o);
        if (lane >= o) run2 += tt;
      }
      const unsigned int pre = run2 - gs;  // count in strictly higher bins
      const unsigned int rem = (unsigned int)remaining;
      if (pre < rem && pre + gs >= rem) {  // exactly one lane hits
        unsigned int above;
        int digit;
        if (pre + c0 >= rem) { digit = bHi; above = pre; }
        else if (pre + c0 + c1 >= rem) { digit = bHi - 1; above = pre + c0; }
        else if (pre + c0 + c1 + c2 >= rem) { digit = bHi - 2; above = pre + c0 + c1; }
        else { digit = bHi - 3; above = pre + c0 + c1 + c2; }
        shPrefix = prefix | ((unsigned int)digit << shift);
        shRemaining = remaining - (int)above;
      }
    }
    __syncthreads();
    prefix = shPrefix;
    remaining = shRemaining;
    __syncthreads();
  }
  const float thr = __uint_as_float(prefix);  // exact kk-th largest value
  for (int j = tid * 4; j < NN; j += 2048) {
    const f32x4 cv = *reinterpret_cast<const f32x4*>(&comb[j]);
    f32x4 ov;
    ov[0] = (cv[0] >= thr && cv[0] > 0.0f) ? 1.0f : 0.0f;
    ov[1] = (cv[1] >= thr && cv[1] > 0.0f) ? 1.0f : 0.0f;
    ov[2] = (cv[2] >= thr && cv[2] > 0.0f) ? 1.0f : 0.0f;
    ov[3] = (cv[3] >= thr && cv[3] > 0.0f) ? 1.0f : 0.0f;
    __builtin_nontemporal_store(ov, reinterpret_cast<f32x4*>(&out1[obase + j]));
  }
}

// ---------------------------------------------------------------------------
// Kernel F: h_prime = attention @ Wh (sparse x dense), then ELU.
// ---------------------------------------------------------------------------
__global__ void __launch_bounds__(256) k_hprime(
    const int* __restrict__ nbr, const int* __restrict__ deg,
    const float* __restrict__ att, const float* __restrict__ Wh,
    float* __restrict__ out0) {
  __shared__ int scol[MAXD];
  __shared__ float sval[MAXD];
  const int row = blockIdx.x;
  const int c = threadIdx.x;
  const int d = deg[row];
  const int* cols = nbr + (size_t)row * MAXD;
  const float* arow = att + (size_t)row * MAXD;
  for (int t = threadIdx.x; t < d; t += 256) {
    scol[t] = cols[t];
    sval[t] = arow[t];
  }
  __syncthreads();
  float a0 = 0.0f, a1 = 0.0f, a2 = 0.0f, a3 = 0.0f;
  int t = 0;
  for (; t + 4 <= d; t += 4) {
    a0 += sval[t + 0] * Wh[(size_t)scol[t + 0] * KFOUT + c];
    a1 += sval[t + 1] * Wh[(size_t)scol[t + 1] * KFOUT + c];
    a2 += sval[t + 2] * Wh[(size_t)scol[t + 2] * KFOUT + c];
    a3 += sval[t + 3] * Wh[(size_t)scol[t + 3] * KFOUT + c];
  }
  for (; t < d; ++t) a0 += sval[t] * Wh[(size_t)scol[t] * KFOUT + c];
  const float acc = (a0 + a1) + (a2 + a3);
  out0[(size_t)row * KFOUT + c] = acc > 0.0f ? acc : expm1f(acc);
}

extern "C" void kernel_launch(void* const* d_in, const int* in_sizes, int n_in,
                              void* d_out, int out_size, void* d_ws, size_t ws_size,
                              hipStream_t stream) {
  const float* h = (const float*)d_in[0];
  const float* adj = (const float*)d_in[1];
  const float* W = (const float*)d_in[2];
  const float* a = (const float*)d_in[3];

  float* out0 = (float*)d_out;                  // [8192, 256] elu(h_prime)
  float* out1 = out0 + (size_t)NN * KFOUT;      // [8192, 8192] adj_resize

  // workspace layout (~33.9 MB)
  float* Wh = (float*)d_ws;                        // 8192*256
  float* Wh1 = Wh + (size_t)NN * KFOUT;            // 8192
  float* Wh2 = Wh1 + NN;                           // 8192
  float* mrow = Wh2 + NN;                          // 8192
  float* Zrow = mrow + NN;                         // 8192
  float* att = Zrow + NN;                          // 8192*MAXD
  float* edgesF = att + (size_t)NN * MAXD;         // 8192*MAXD int2
  int2* edgesT = (int2*)edgesF;
  int* nbr = (int*)(edgesF + (size_t)NN * MAXD * 2);  // 8192*MAXD
  int* deg = nbr + (size_t)NN * MAXD;              // 8192
  int* s2v = deg + NN;                             // 8192
  short* qb8 = (short*)(s2v + NN);                 // 8192*8 shorts (128 KB)

  k_build_csr<<<NN / 4, 256, 0, stream>>>(adj, nbr, deg, s2v);
  dim3 ggrid(KFOUT / 64, NN / 64);
  k_gemm<<<ggrid, 256, 0, stream>>>(h, W, Wh);
  k_rowdots<<<NN, 256, 0, stream>>>(Wh, a, Wh1, Wh2);
  k_stats<<<NN / 4, 256, 0, stream>>>(nbr, deg, Wh1, Wh2, mrow, Zrow);
  k_att<<<NN / 4, 256, 0, stream>>>(nbr, deg, Wh1, Wh2, mrow, Zrow, att, edgesT, qb8);
  k_twostep<<<NN, 512, 0, stream>>>(nbr, deg, s2v, att, edgesT, qb8, out1);
  k_hprime<<<NN, 256, 0, stream>>>(nbr, deg, att, Wh, out0);
}

// Round 10
// 516.154 us; speedup vs baseline: 1.2553x; 1.2553x over previous
//
#include <hip/hip_runtime.h>
#include <cstdint>
#include <cstddef>

#define NN 8192
#define KFIN 1024
#define KFOUT 256
#define MAXD 192
#define LRALPHA 0.2f

typedef float f32x4 __attribute__((ext_vector_type(4)));

// ---------------------------------------------------------------------------
// Kernel A: dense adj -> CSR neighbor lists (stable ascending-column order via
// 4x ballot on float4 nontemporal loads), degree, s2 = off-diagonal degree.
// ---------------------------------------------------------------------------
__global__ void __launch_bounds__(256) k_build_csr(
    const float* __restrict__ adj, int* __restrict__ nbr,
    int* __restrict__ deg, int* __restrict__ s2v) {
  const int wave = threadIdx.x >> 6;
  const int lane = threadIdx.x & 63;
  const int row = blockIdx.x * 4 + wave;
  const float* arow = adj + (size_t)row * NN;
  int* outp = nbr + (size_t)row * MAXD;
  int count = 0;
  int dflag = 0;
  const unsigned long long below = (1ull << lane) - 1ull;
  for (int c0 = 0; c0 < NN; c0 += 256) {
    const int c = c0 + lane * 4;
    const f32x4 v = __builtin_nontemporal_load(
        reinterpret_cast<const f32x4*>(arow + c));
    const unsigned long long m0 = __ballot(v[0] > 0.0f);
    const unsigned long long m1 = __ballot(v[1] > 0.0f);
    const unsigned long long m2 = __ballot(v[2] > 0.0f);
    const unsigned long long m3 = __ballot(v[3] > 0.0f);
    int pos = count + (int)(__popcll(m0 & below) + __popcll(m1 & below) +
                            __popcll(m2 & below) + __popcll(m3 & below));
    if (v[0] > 0.0f) { if (pos < MAXD) outp[pos] = c + 0; ++pos; if (c + 0 == row) dflag = 1; }
    if (v[1] > 0.0f) { if (pos < MAXD) outp[pos] = c + 1; ++pos; if (c + 1 == row) dflag = 1; }
    if (v[2] > 0.0f) { if (pos < MAXD) outp[pos] = c + 2; ++pos; if (c + 2 == row) dflag = 1; }
    if (v[3] > 0.0f) { if (pos < MAXD) outp[pos] = c + 3; ++pos; if (c + 3 == row) dflag = 1; }
    count += (int)(__popcll(m0) + __popcll(m1) + __popcll(m2) + __popcll(m3));
  }
  const int anyd = __any(dflag) ? 1 : 0;
  if (lane == 0) {
    deg[row] = count < MAXD ? count : MAXD;
    s2v[row] = count - anyd;
  }
}

// ---------------------------------------------------------------------------
// Kernel B: Wh = h @ W, f32 tiled GEMM (64x64 tile, 4x4 per thread, BK=16).
// ---------------------------------------------------------------------------
__global__ void __launch_bounds__(256) k_gemm(
    const float* __restrict__ A, const float* __restrict__ B,
    float* __restrict__ C) {
  __shared__ float As[16][65];
  __shared__ float Bs[16][65];
  const int tid = threadIdx.x;
  const int brow = blockIdx.y * 64;
  const int bcol = blockIdx.x * 64;
  const int tx = tid & 15;
  const int ty = tid >> 4;
  float acc[4][4];
#pragma unroll
  for (int i = 0; i < 4; ++i)
#pragma unroll
    for (int j = 0; j < 4; ++j) acc[i][j] = 0.0f;
  const int ar = tid >> 2;
  const int ac = (tid & 3) << 2;
  const int br = tid >> 4;
  const int bc = (tid & 15) << 2;
  for (int k0 = 0; k0 < KFIN; k0 += 16) {
    const float4 av =
        *reinterpret_cast<const float4*>(A + (size_t)(brow + ar) * KFIN + k0 + ac);
    const float4 bv =
        *reinterpret_cast<const float4*>(B + (size_t)(k0 + br) * KFOUT + bcol + bc);
    As[ac + 0][ar] = av.x;
    As[ac + 1][ar] = av.y;
    As[ac + 2][ar] = av.z;
    As[ac + 3][ar] = av.w;
    Bs[br][bc + 0] = bv.x;
    Bs[br][bc + 1] = bv.y;
    Bs[br][bc + 2] = bv.z;
    Bs[br][bc + 3] = bv.w;
    __syncthreads();
#pragma unroll
    for (int kk = 0; kk < 16; ++kk) {
      const float a0 = As[kk][ty * 4 + 0];
      const float a1 = As[kk][ty * 4 + 1];
      const float a2 = As[kk][ty * 4 + 2];
      const float a3 = As[kk][ty * 4 + 3];
      const float b0 = Bs[kk][tx * 4 + 0];
      const float b1 = Bs[kk][tx * 4 + 1];
      const float b2 = Bs[kk][tx * 4 + 2];
      const float b3 = Bs[kk][tx * 4 + 3];
      acc[0][0] += a0 * b0; acc[0][1] += a0 * b1; acc[0][2] += a0 * b2; acc[0][3] += a0 * b3;
      acc[1][0] += a1 * b0; acc[1][1] += a1 * b1; acc[1][2] += a1 * b2; acc[1][3] += a1 * b3;
      acc[2][0] += a2 * b0; acc[2][1] += a2 * b1; acc[2][2] += a2 * b2; acc[2][3] += a2 * b3;
      acc[3][0] += a3 * b0; acc[3][1] += a3 * b1; acc[3][2] += a3 * b2; acc[3][3] += a3 * b3;
    }
    __syncthreads();
  }
#pragma unroll
  for (int i = 0; i < 4; ++i) {
#pragma unroll
    for (int j = 0; j < 4; ++j) {
      C[(size_t)(brow + ty * 4 + i) * KFOUT + bcol + tx * 4 + j] = acc[i][j];
    }
  }
}

// ---------------------------------------------------------------------------
// Kernel C: Wh1 = Wh @ a[:256], Wh2 = Wh @ a[256:], one block per row.
// ---------------------------------------------------------------------------
__global__ void __launch_bounds__(256) k_rowdots(
    const float* __restrict__ Wh, const float* __restrict__ a,
    float* __restrict__ Wh1, float* __restrict__ Wh2) {
  __shared__ float sA[256];
  __shared__ float sB[256];
  const int row = blockIdx.x;
  const int t = threadIdx.x;
  const float w = Wh[(size_t)row * KFOUT + t];
  sA[t] = w * a[t];
  sB[t] = w * a[KFOUT + t];
  __syncthreads();
  for (int s = 128; s > 0; s >>= 1) {
    if (t < s) {
      sA[t] += sA[t + s];
      sB[t] += sB[t + s];
    }
    __syncthreads();
  }
  if (t == 0) {
    Wh1[row] = sA[0];
    Wh2[row] = sB[0];
  }
}

// ---------------------------------------------------------------------------
// Kernel D1: per-row softmax stats (max m, denom Z) over neighbor list.
// ---------------------------------------------------------------------------
__global__ void __launch_bounds__(256) k_stats(
    const int* __restrict__ nbr, const int* __restrict__ deg,
    const float* __restrict__ Wh1, const float* __restrict__ Wh2,
    float* __restrict__ mrow, float* __restrict__ Zrow) {
  const int wave = threadIdx.x >> 6;
  const int lane = threadIdx.x & 63;
  const int row = blockIdx.x * 4 + wave;
  const int d = deg[row];
  const int* cols = nbr + (size_t)row * MAXD;
  const float w1 = Wh1[row];
  float mx = -1e30f;
  for (int t = lane; t < d; t += 64) {
    float e = w1 + Wh2[cols[t]];
    e = e > 0.0f ? e : LRALPHA * e;
    mx = fmaxf(mx, e);
  }
  for (int o = 32; o > 0; o >>= 1) mx = fmaxf(mx, __shfl_xor(mx, o));
  float sum = 0.0f;
  for (int t = lane; t < d; t += 64) {
    float e = w1 + Wh2[cols[t]];
    e = e > 0.0f ? e : LRALPHA * e;
    sum += expf(e - mx);
  }
  for (int o = 32; o > 0; o >>= 1) sum += __shfl_xor(sum, o);
  if (lane == 0) {
    mrow[row] = mx;
    Zrow[row] = (d > 0) ? sum : 1.0f;
  }
}

// ---------------------------------------------------------------------------
// Kernel D2: attention CSR values + packed transpose-edge values + per-row
// packed octant segments pq16[row][w] = qs | (qe<<8) (cols ascending ->
// octant segments contiguous; qs,qe <= 192 fit a byte each).
// ---------------------------------------------------------------------------
__global__ void __launch_bounds__(256) k_att(
    const int* __restrict__ nbr, const int* __restrict__ deg,
    const float* __restrict__ Wh1, const float* __restrict__ Wh2,
    const float* __restrict__ mrow, const float* __restrict__ Zrow,
    float* __restrict__ att, int2* __restrict__ edgesT,
    unsigned short* __restrict__ pq16) {
  const int wave = threadIdx.x >> 6;
  const int lane = threadIdx.x & 63;
  const int row = blockIdx.x * 4 + wave;
  const int d = deg[row];
  const int* cols = nbr + (size_t)row * MAXD;
  const float w1r = Wh1[row];
  const float w2r = Wh2[row];
  const float mr = mrow[row];
  const float invZr = 1.0f / Zrow[row];
  int b[7] = {0, 0, 0, 0, 0, 0, 0};
  for (int t0 = 0; t0 < d; t0 += 64) {
    const int t = t0 + lane;
    const bool act = t < d;
    const int j = act ? cols[t] : 0x7fffffff;
#pragma unroll
    for (int m = 1; m <= 7; ++m)
      b[m - 1] += (int)__popcll(__ballot(act && j < m * 1024));
    if (act) {
      float e = w1r + Wh2[j];
      e = e > 0.0f ? e : LRALPHA * e;
      att[(size_t)row * MAXD + t] = expf(e - mr) * invZr;
      float e2 = Wh1[j] + w2r;
      e2 = e2 > 0.0f ? e2 : LRALPHA * e2;
      const float v = expf(e2 - mrow[j]) / Zrow[j];
      edgesT[(size_t)row * MAXD + t] = make_int2(j, __float_as_int(v));
    }
  }
  if (lane == 0) {
    unsigned short* q = pq16 + (size_t)row * 8;
    int prev = 0;
#pragma unroll
    for (int w = 0; w < 7; ++w) {
      q[w] = (unsigned short)(prev | (b[w] << 8));
      prev = b[w];
    }
    q[7] = (unsigned short)(prev | (d << 8));
  }
}

// ---------------------------------------------------------------------------
// Kernel E: per row i, 512 threads (8 waves), comb row in LDS.
// Octant-partitioned scatter (16-lane groups, fixed-trip depth-4 pipeline;
// per-lane pq registers + shfl replace the old LDS packw table). LDS atomics
// are wave-exclusive per octant -> replay-deterministic.
// Select of the s2-th largest: 11-bit histogram pass (2048 u16-packed bins)
// -> compact the chosen bin's candidates (<= a few hundred) into LDS ->
// wave-0 bit-serial select over the remaining 21 bits (no barriers, no dense
// sweeps). Dense byte-pass fallback if candidates > 512. Dense 8192-sweeps:
// 3 total (hist, compact, final write) vs 5 before.
// ---------------------------------------------------------------------------
__global__ void __launch_bounds__(512) k_twostep(
    const int* __restrict__ nbr, const int* __restrict__ deg,
    const int* __restrict__ s2v, const float* __restrict__ att,
    const int2* __restrict__ edgesT, const unsigned short* __restrict__ pq16,
    float* __restrict__ out1) {
  __shared__ float comb[NN];                // 32768 B
  __shared__ float wvals[MAXD];             //   768 B
  __shared__ unsigned short kcols[MAXD];    //   384 B
  __shared__ unsigned int hist[1024];       //  4096 B (2048 u16 bins packed)
  __shared__ unsigned int scomp[512];       //  2048 B
  __shared__ unsigned int shPrefix;
  __shared__ int shRemaining;
  __shared__ int shNc;
  const int tid = threadIdx.x;
  const int wave = tid >> 6;
  const int lane = tid & 63;
  const int row = blockIdx.x;
  const f32x4 z4 = {0.0f, 0.0f, 0.0f, 0.0f};
  for (int j = tid * 4; j < NN; j += 2048)
    *reinterpret_cast<f32x4*>(&comb[j]) = z4;
  const int d = deg[row];
  const size_t rowbase = (size_t)row * MAXD;
  for (int t = tid; t < d; t += 512) {
    kcols[t] = (unsigned short)nbr[rowbase + t];
    wvals[t] = att[rowbase + t];
  }
  // per-lane pq registers for this wave's octant: slot i covers t = lane+64i
  unsigned pq0 = 0, pq1 = 0, pq2 = 0;
  if (lane < d)        pq0 = pq16[(size_t)nbr[rowbase + lane] * 8 + wave];
  if (lane + 64 < d)   pq1 = pq16[(size_t)nbr[rowbase + lane + 64] * 8 + wave];
  if (lane + 128 < d)  pq2 = pq16[(size_t)nbr[rowbase + lane + 128] * 8 + wave];
  if (tid == 0) shNc = 0;
  __syncthreads();
  // --- phase A: fixed-trip depth-4 pipelined scatter, 16-lane groups
  {
    const int grp = lane >> 4;   // 0..3
    const int sub = lane & 15;   // 0..15
    const int nsteps = (d + 3) >> 2;
    int2 eA = make_int2(0, 0), eB = make_int2(0, 0);
    int2 eC = make_int2(0, 0), eD = make_int2(0, 0);
    float wA = 0.0f, wB = 0.0f, wC = 0.0f, wD = 0.0f;
    bool pA_ = false, pB_ = false, pC_ = false, pD_ = false;
#define PA_ISSUE(E_, W_, P_, S_)                                       \
    {                                                                   \
      const int t_ = (S_) * 4 + grp;                                    \
      const bool v_ = t_ < d;                                           \
      const int src_ = t_ & 63;                                         \
      const unsigned q0_ = __shfl(pq0, src_);                           \
      const unsigned q1_ = __shfl(pq1, src_);                           \
      const unsigned q2_ = __shfl(pq2, src_);                           \
      const unsigned pk_ = t_ < 64 ? q0_ : (t_ < 128 ? q1_ : q2_);      \
      const int qs_ = (int)(pk_ & 255u);                                \
      const int qe_ = (int)(pk_ >> 8);                                  \
      P_ = v_ && (qs_ + sub) < qe_;                                     \
      W_ = v_ ? wvals[t_] : 0.0f;                                       \
      E_ = make_int2(0, 0);                                             \
      if (P_) {                                                         \
        const int c_ = (int)kcols[t_];                                  \
        E_ = edgesT[(size_t)c_ * MAXD + qs_ + sub];                     \
      }                                                                 \
    }
    if (nsteps > 0) PA_ISSUE(eA, wA, pA_, 0);
    if (nsteps > 1) PA_ISSUE(eB, wB, pB_, 1);
    if (nsteps > 2) PA_ISSUE(eC, wC, pC_, 2);
    if (nsteps > 3) PA_ISSUE(eD, wD, pD_, 3);
    for (int s = 0; s < nsteps; ++s) {
      const int2 e = eA; const float w = wA; const bool p = pA_;
      eA = eB; wA = wB; pA_ = pB_;
      eB = eC; wB = wC; pB_ = pC_;
      eC = eD; wC = wD; pC_ = pD_;
      if (s + 4 < nsteps) PA_ISSUE(eD, wD, pD_, s + 4);
      if (p) atomicAdd(&comb[e.x], w * __int_as_float(e.y));
    }
#undef PA_ISSUE
  }
  // --- phase B: cleanup for rare octant segments longer than 16
#pragma unroll
  for (int i = 0; i < 3; ++i) {
    const int tbase = 64 * i;
    const unsigned pk = (i == 0) ? pq0 : (i == 1 ? pq1 : pq2);
    const bool big = (tbase + lane < d) &&
                     (((int)(pk >> 8) - (int)(pk & 255u)) > 16);
    unsigned long long m = __ballot(big);
    while (m) {
      const int l = (int)__ffsll((long long)m) - 1;
      m &= m - 1;
      const unsigned pkk = __shfl(pk, l);
      const int tt = tbase + l;
      const int qs = (int)(pkk & 255u);
      const int qe = (int)(pkk >> 8);
      const float w = wvals[tt];
      const int base = (int)kcols[tt] * MAXD;
      for (int off = qs + 16 + lane; off < qe; off += 64) {
        const int2 e = edgesT[(size_t)base + off];
        atomicAdd(&comb[e.x], w * __int_as_float(e.y));
      }
    }
  }
  // --- add row's own attention values (wave's own octant segment), then
  //     zero the diagonal (owner wave, before the barrier).
  {
    const unsigned pr = pq16[(size_t)row * 8 + wave];
    const int qlo = (int)(pr & 255u);
    const int qhi = (int)(pr >> 8);
    for (int t = qlo + lane; t < qhi; t += 64) comb[(int)kcols[t]] += wvals[t];
    if (lane == 0 && wave == (row >> 10)) comb[row] = 0.0f;
  }
  __syncthreads();
  const int kk = s2v[row];
  const size_t obase = (size_t)row * NN;
  if (kk <= 0) {
    for (int j = tid * 4; j < NN; j += 2048)
      __builtin_nontemporal_store(z4, reinterpret_cast<f32x4*>(&out1[obase + j]));
    return;
  }
  // --- pass 0: 11-bit histogram (2048 bins, u16-packed pairs). Zeros skipped
  //     (threshold provably > 0).
  hist[tid] = 0u;
  hist[tid + 512] = 0u;
  __syncthreads();
  for (int j = tid * 4; j < NN; j += 2048) {
    const f32x4 cv = *reinterpret_cast<const f32x4*>(&comb[j]);
#pragma unroll
    for (int q = 0; q < 4; ++q) {
      const unsigned int u = __float_as_uint(cv[q]);
      if (u != 0u) {
        const unsigned bin = u >> 21;
        atomicAdd(&hist[bin >> 1], 1u << ((bin & 1u) << 4));
      }
    }
  }
  __syncthreads();
  if (tid < 64) {
    // lane owns 32 bins descending (lane 0 = highest): words wbase..wbase+15
    const int wbase = 1008 - 16 * lane;
    unsigned gs = 0;
    for (int i = 0; i < 16; ++i) {
      const unsigned c = hist[wbase + i];
      gs += (c >> 16) + (c & 0xFFFFu);
    }
    unsigned run = gs;
    for (int o = 1; o < 64; o <<= 1) {
      const unsigned t2 = __shfl_up(run, o);
      if (lane >= o) run += t2;
    }
    const unsigned pre = run - gs;
    const unsigned rem = (unsigned)kk;
    if (pre < rem && pre + gs >= rem) {
      unsigned acc = pre, above = 0;
      int digit = -1;
      for (int i = 15; i >= 0; --i) {  // word 15 holds the highest bins
        const unsigned c = hist[wbase + i];
        const unsigned chi = c >> 16, clo = c & 0xFFFFu;
        if (digit < 0 && acc + chi >= rem) { digit = 2 * (wbase + i) + 1; above = acc; }
        if (digit < 0 && acc + chi + clo >= rem) { digit = 2 * (wbase + i); above = acc + chi; }
        acc += chi + clo;
      }
      shPrefix = (unsigned)digit;
      shRemaining = (int)(rem - above);
    }
  }
  __syncthreads();
  const unsigned digit11 = shPrefix;
  const int rem2 = shRemaining;
  // --- compact candidates of the chosen 11-bit bin (order-independent)
  for (int j = tid * 4; j < NN; j += 2048) {
    const f32x4 cv = *reinterpret_cast<const f32x4*>(&comb[j]);
#pragma unroll
    for (int q = 0; q < 4; ++q) {
      const unsigned int u = __float_as_uint(cv[q]);
      if (u != 0u && (u >> 21) == digit11) {
        const int idx = atomicAdd(&shNc, 1);
        if (idx < 512) scomp[idx] = u;
      }
    }
  }
  __syncthreads();
  const int nc = shNc;
  unsigned thr_u;
  if (nc <= 512) {
    // --- wave-0 bit-serial select over the low 21 bits of <=512 candidates
    if (wave == 0) {
      unsigned v0 = 0, v1 = 0, v2 = 0, v3 = 0, v4 = 0, v5 = 0, v6 = 0, v7 = 0;
      bool m0 = false, m1 = false, m2 = false, m3 = false;
      bool m4 = false, m5 = false, m6 = false, m7 = false;
#define LDV(I) { const int ix = lane + 64 * I; \
                 if (ix < nc) { v##I = scomp[ix] & 0x1FFFFFu; m##I = true; } }
      LDV(0) LDV(1) LDV(2) LDV(3) LDV(4) LDV(5) LDV(6) LDV(7)
#undef LDV
      unsigned sel = 0;
      int r = rem2;
      for (int b = 20; b >= 0; --b) {
        const unsigned pat = (sel << 1) | 1u;
        int cnt = (int)(m0 && (v0 >> b) == pat) + (int)(m1 && (v1 >> b) == pat) +
                  (int)(m2 && (v2 >> b) == pat) + (int)(m3 && (v3 >> b) == pat) +
                  (int)(m4 && (v4 >> b) == pat) + (int)(m5 && (v5 >> b) == pat) +
                  (int)(m6 && (v6 >> b) == pat) + (int)(m7 && (v7 >> b) == pat);
        for (int o = 32; o > 0; o >>= 1) cnt += __shfl_xor(cnt, o);
        if (cnt >= r) sel = pat; else { r -= cnt; sel <<= 1; }
      }
      if (lane == 0) shPrefix = (digit11 << 21) | sel;
    }
    __syncthreads();
    thr_u = shPrefix;
  } else {
    // --- fallback: block-wide byte passes over dense comb (bits 20..0)
    unsigned prefix = digit11 << 21;
    int remaining = rem2;
    for (int pass = 0; pass < 3; ++pass) {
      const int shift = (pass == 0) ? 13 : ((pass == 1) ? 5 : 0);
      const unsigned pmask = (pass == 0) ? 0xFFE00000u
                           : ((pass == 1) ? 0xFFFFE000u : 0xFFFFFFE0u);
      const unsigned bmask = (pass == 2) ? 31u : 255u;
      if (tid < 256) hist[tid] = 0u;
      __syncthreads();
      for (int j = tid * 4; j < NN; j += 2048) {
        const f32x4 cv = *reinterpret_cast<const f32x4*>(&comb[j]);
#pragma unroll
        for (int q = 0; q < 4; ++q) {
          const unsigned int u = __float_as_uint(cv[q]);
          if (u != 0u && (u & pmask) == prefix)
            atomicAdd(&hist[(u >> shift) & bmask], 1u);
        }
      }
      __syncthreads();
      if (tid < 64) {
        const int bHi = 255 - 4 * lane;
        const unsigned c0 = hist[bHi];
        const unsigned c1 = hist[bHi - 1];
        const unsigned c2 = hist[bHi - 2];
        const unsigned c3 = hist[bHi - 3];
        const unsigned gs = c0 + c1 + c2 + c3;
        unsigned run2 = gs;
        for (int o = 1; o < 64; o <<= 1) {
          const unsigned t2 = __shfl_up(run2, o);
          if (lane >= o) run2 += t2;
        }
        const unsigned pre = run2 - gs;
        const unsigned rem = (unsigned)remaining;
        if (pre < rem && pre + gs >= rem) {
          unsigned above;
          int digit;
          if (pre + c0 >= rem) { digit = bHi; above = pre; }
          else if (pre + c0 + c1 >= rem) { digit = bHi - 1; above = pre + c0; }
          else if (pre + c0 + c1 + c2 >= rem) { digit = bHi - 2; above = pre + c0 + c1; }
          else { digit = bHi - 3; above = pre + c0 + c1 + c2; }
          shPrefix = prefix | ((unsigned)digit << shift);
          shRemaining = remaining - (int)above;
        }
      }
      __syncthreads();
      prefix = shPrefix;
      remaining = shRemaining;
      __syncthreads();
    }
    thr_u = prefix;
  }
  const float thr = __uint_as_float(thr_u);  // exact kk-th largest value
  for (int j = tid * 4; j < NN; j += 2048) {
    const f32x4 cv = *reinterpret_cast<const f32x4*>(&comb[j]);
    f32x4 ov;
    ov[0] = (cv[0] >= thr && cv[0] > 0.0f) ? 1.0f : 0.0f;
    ov[1] = (cv[1] >= thr && cv[1] > 0.0f) ? 1.0f : 0.0f;
    ov[2] = (cv[2] >= thr && cv[2] > 0.0f) ? 1.0f : 0.0f;
    ov[3] = (cv[3] >= thr && cv[3] > 0.0f) ? 1.0f : 0.0f;
    __builtin_nontemporal_store(ov, reinterpret_cast<f32x4*>(&out1[obase + j]));
  }
}

// ---------------------------------------------------------------------------
// Kernel F: h_prime = attention @ Wh (sparse x dense), then ELU.
// ---------------------------------------------------------------------------
__global__ void __launch_bounds__(256) k_hprime(
    const int* __restrict__ nbr, const int* __restrict__ deg,
    const float* __restrict__ att, const float* __restrict__ Wh,
    float* __restrict__ out0) {
  __shared__ int scol[MAXD];
  __shared__ float sval[MAXD];
  const int row = blockIdx.x;
  const int c = threadIdx.x;
  const int d = deg[row];
  const int* cols = nbr + (size_t)row * MAXD;
  const float* arow = att + (size_t)row * MAXD;
  for (int t = threadIdx.x; t < d; t += 256) {
    scol[t] = cols[t];
    sval[t] = arow[t];
  }
  __syncthreads();
  float a0 = 0.0f, a1 = 0.0f, a2 = 0.0f, a3 = 0.0f;
  int t = 0;
  for (; t + 4 <= d; t += 4) {
    a0 += sval[t + 0] * Wh[(size_t)scol[t + 0] * KFOUT + c];
    a1 += sval[t + 1] * Wh[(size_t)scol[t + 1] * KFOUT + c];
    a2 += sval[t + 2] * Wh[(size_t)scol[t + 2] * KFOUT + c];
    a3 += sval[t + 3] * Wh[(size_t)scol[t + 3] * KFOUT + c];
  }
  for (; t < d; ++t) a0 += sval[t] * Wh[(size_t)scol[t] * KFOUT + c];
  const float acc = (a0 + a1) + (a2 + a3);
  out0[(size_t)row * KFOUT + c] = acc > 0.0f ? acc : expm1f(acc);
}

extern "C" void kernel_launch(void* const* d_in, const int* in_sizes, int n_in,
                              void* d_out, int out_size, void* d_ws, size_t ws_size,
                              hipStream_t stream) {
  const float* h = (const float*)d_in[0];
  const float* adj = (const float*)d_in[1];
  const float* W = (const float*)d_in[2];
  const float* a = (const float*)d_in[3];

  float* out0 = (float*)d_out;                  // [8192, 256] elu(h_prime)
  float* out1 = out0 + (size_t)NN * KFOUT;      // [8192, 8192] adj_resize

  // workspace layout (~33.9 MB)
  float* Wh = (float*)d_ws;                        // 8192*256
  float* Wh1 = Wh + (size_t)NN * KFOUT;            // 8192
  float* Wh2 = Wh1 + NN;                           // 8192
  float* mrow = Wh2 + NN;                          // 8192
  float* Zrow = mrow + NN;                         // 8192
  float* att = Zrow + NN;                          // 8192*MAXD
  float* edgesF = att + (size_t)NN * MAXD;         // 8192*MAXD int2
  int2* edgesT = (int2*)edgesF;
  int* nbr = (int*)(edgesF + (size_t)NN * MAXD * 2);  // 8192*MAXD
  int* deg = nbr + (size_t)NN * MAXD;              // 8192
  int* s2v = deg + NN;                             // 8192
  unsigned short* pq16 = (unsigned short*)(s2v + NN);  // 8192*8 u16 (128 KB)

  k_build_csr<<<NN / 4, 256, 0, stream>>>(adj, nbr, deg, s2v);
  dim3 ggrid(KFOUT / 64, NN / 64);
  k_gemm<<<ggrid, 256, 0, stream>>>(h, W, Wh);
  k_rowdots<<<NN, 256, 0, stream>>>(Wh, a, Wh1, Wh2);
  k_stats<<<NN / 4, 256, 0, stream>>>(nbr, deg, Wh1, Wh2, mrow, Zrow);
  k_att<<<NN / 4, 256, 0, stream>>>(nbr, deg, Wh1, Wh2, mrow, Zrow, att, edgesT, pq16);
  k_twostep<<<NN, 512, 0, stream>>>(nbr, deg, s2v, att, edgesT, pq16, out1);
  k_hprime<<<NN, 256, 0, stream>>>(nbr, deg, att, Wh, out0);
}

// Round 11
// 482.019 us; speedup vs baseline: 1.3442x; 1.0708x over previous
//
#include <hip/hip_runtime.h>
#include <cstdint>
#include <cstddef>

#define NN 8192
#define KFIN 1024
#define KFOUT 256
#define MAXD 192
#define LRALPHA 0.2f

typedef float f32x4 __attribute__((ext_vector_type(4)));

// ---------------------------------------------------------------------------
// Kernel A: dense adj -> CSR neighbor lists (stable ascending-column order via
// 4x ballot on float4 nontemporal loads), degree, s2 = off-diagonal degree.
// ---------------------------------------------------------------------------
__global__ void __launch_bounds__(256) k_build_csr(
    const float* __restrict__ adj, int* __restrict__ nbr,
    int* __restrict__ deg, int* __restrict__ s2v) {
  const int wave = threadIdx.x >> 6;
  const int lane = threadIdx.x & 63;
  const int row = blockIdx.x * 4 + wave;
  const float* arow = adj + (size_t)row * NN;
  int* outp = nbr + (size_t)row * MAXD;
  int count = 0;
  int dflag = 0;
  const unsigned long long below = (1ull << lane) - 1ull;
  for (int c0 = 0; c0 < NN; c0 += 256) {
    const int c = c0 + lane * 4;
    const f32x4 v = __builtin_nontemporal_load(
        reinterpret_cast<const f32x4*>(arow + c));
    const unsigned long long m0 = __ballot(v[0] > 0.0f);
    const unsigned long long m1 = __ballot(v[1] > 0.0f);
    const unsigned long long m2 = __ballot(v[2] > 0.0f);
    const unsigned long long m3 = __ballot(v[3] > 0.0f);
    int pos = count + (int)(__popcll(m0 & below) + __popcll(m1 & below) +
                            __popcll(m2 & below) + __popcll(m3 & below));
    if (v[0] > 0.0f) { if (pos < MAXD) outp[pos] = c + 0; ++pos; if (c + 0 == row) dflag = 1; }
    if (v[1] > 0.0f) { if (pos < MAXD) outp[pos] = c + 1; ++pos; if (c + 1 == row) dflag = 1; }
    if (v[2] > 0.0f) { if (pos < MAXD) outp[pos] = c + 2; ++pos; if (c + 2 == row) dflag = 1; }
    if (v[3] > 0.0f) { if (pos < MAXD) outp[pos] = c + 3; ++pos; if (c + 3 == row) dflag = 1; }
    count += (int)(__popcll(m0) + __popcll(m1) + __popcll(m2) + __popcll(m3));
  }
  const int anyd = __any(dflag) ? 1 : 0;
  if (lane == 0) {
    deg[row] = count < MAXD ? count : MAXD;
    s2v[row] = count - anyd;
  }
}

// ---------------------------------------------------------------------------
// Kernel B: Wh = h @ W, f32 tiled GEMM (64x64 tile, 4x4 per thread, BK=32).
// BK=32 halves the barrier count vs BK=16 and doubles load width per sync.
// ---------------------------------------------------------------------------
__global__ void __launch_bounds__(256) k_gemm(
    const float* __restrict__ A, const float* __restrict__ B,
    float* __restrict__ C) {
  __shared__ float As[32][65];
  __shared__ float Bs[32][65];
  const int tid = threadIdx.x;
  const int brow = blockIdx.y * 64;
  const int bcol = blockIdx.x * 64;
  const int tx = tid & 15;
  const int ty = tid >> 4;
  float acc[4][4];
#pragma unroll
  for (int i = 0; i < 4; ++i)
#pragma unroll
    for (int j = 0; j < 4; ++j) acc[i][j] = 0.0f;
  const int ar = tid >> 2;
  const int ac = (tid & 3) << 2;
  const int br = tid >> 4;
  const int bc = (tid & 15) << 2;
  for (int k0 = 0; k0 < KFIN; k0 += 32) {
    const float4 av0 =
        *reinterpret_cast<const float4*>(A + (size_t)(brow + ar) * KFIN + k0 + ac);
    const float4 av1 =
        *reinterpret_cast<const float4*>(A + (size_t)(brow + ar) * KFIN + k0 + 16 + ac);
    const float4 bv0 =
        *reinterpret_cast<const float4*>(B + (size_t)(k0 + br) * KFOUT + bcol + bc);
    const float4 bv1 =
        *reinterpret_cast<const float4*>(B + (size_t)(k0 + 16 + br) * KFOUT + bcol + bc);
    As[ac + 0][ar] = av0.x;
    As[ac + 1][ar] = av0.y;
    As[ac + 2][ar] = av0.z;
    As[ac + 3][ar] = av0.w;
    As[16 + ac + 0][ar] = av1.x;
    As[16 + ac + 1][ar] = av1.y;
    As[16 + ac + 2][ar] = av1.z;
    As[16 + ac + 3][ar] = av1.w;
    Bs[br][bc + 0] = bv0.x;
    Bs[br][bc + 1] = bv0.y;
    Bs[br][bc + 2] = bv0.z;
    Bs[br][bc + 3] = bv0.w;
    Bs[16 + br][bc + 0] = bv1.x;
    Bs[16 + br][bc + 1] = bv1.y;
    Bs[16 + br][bc + 2] = bv1.z;
    Bs[16 + br][bc + 3] = bv1.w;
    __syncthreads();
#pragma unroll
    for (int kk = 0; kk < 32; ++kk) {
      const float a0 = As[kk][ty * 4 + 0];
      const float a1 = As[kk][ty * 4 + 1];
      const float a2 = As[kk][ty * 4 + 2];
      const float a3 = As[kk][ty * 4 + 3];
      const float b0 = Bs[kk][tx * 4 + 0];
      const float b1 = Bs[kk][tx * 4 + 1];
      const float b2 = Bs[kk][tx * 4 + 2];
      const float b3 = Bs[kk][tx * 4 + 3];
      acc[0][0] += a0 * b0; acc[0][1] += a0 * b1; acc[0][2] += a0 * b2; acc[0][3] += a0 * b3;
      acc[1][0] += a1 * b0; acc[1][1] += a1 * b1; acc[1][2] += a1 * b2; acc[1][3] += a1 * b3;
      acc[2][0] += a2 * b0; acc[2][1] += a2 * b1; acc[2][2] += a2 * b2; acc[2][3] += a2 * b3;
      acc[3][0] += a3 * b0; acc[3][1] += a3 * b1; acc[3][2] += a3 * b2; acc[3][3] += a3 * b3;
    }
    __syncthreads();
  }
#pragma unroll
  for (int i = 0; i < 4; ++i) {
#pragma unroll
    for (int j = 0; j < 4; ++j) {
      C[(size_t)(brow + ty * 4 + i) * KFOUT + bcol + tx * 4 + j] = acc[i][j];
    }
  }
}

// ---------------------------------------------------------------------------
// Kernel C: Wh1 = Wh @ a[:256], Wh2 = Wh @ a[256:], one block per row.
// ---------------------------------------------------------------------------
__global__ void __launch_bounds__(256) k_rowdots(
    const float* __restrict__ Wh, const float* __restrict__ a,
    float* __restrict__ Wh1, float* __restrict__ Wh2) {
  __shared__ float sA[256];
  __shared__ float sB[256];
  const int row = blockIdx.x;
  const int t = threadIdx.x;
  const float w = Wh[(size_t)row * KFOUT + t];
  sA[t] = w * a[t];
  sB[t] = w * a[KFOUT + t];
  __syncthreads();
  for (int s = 128; s > 0; s >>= 1) {
    if (t < s) {
      sA[t] += sA[t + s];
      sB[t] += sB[t + s];
    }
    __syncthreads();
  }
  if (t == 0) {
    Wh1[row] = sA[0];
    Wh2[row] = sB[0];
  }
}

// ---------------------------------------------------------------------------
// Kernel D1: per-row softmax stats (m, Z) + row-normalized attention values
// + octant split counts qb8 -- all from ONE edge gather (cols/Wh2/exp cached
// in 3 per-lane registers; d <= 192 = 3*64). One wave per row.
// qb8[row][m-1] = count(col < m*1024) for m=1..7; qb8[row][7] = d.
// ---------------------------------------------------------------------------
__global__ void __launch_bounds__(256) k_stats(
    const int* __restrict__ nbr, const int* __restrict__ deg,
    const float* __restrict__ Wh1, const float* __restrict__ Wh2,
    float* __restrict__ mrow, float* __restrict__ Zrow,
    float* __restrict__ att, short* __restrict__ qb8) {
  const int wave = threadIdx.x >> 6;
  const int lane = threadIdx.x & 63;
  const int row = blockIdx.x * 4 + wave;
  const int d = deg[row];
  const size_t rowbase = (size_t)row * MAXD;
  const int* cols = nbr + rowbase;
  const float w1 = Wh1[row];
  int c0 = 0x7fffffff, c1 = 0x7fffffff, c2 = 0x7fffffff;
  float e0 = -1e30f, e1 = -1e30f, e2 = -1e30f;
  const bool a0 = lane < d, a1 = lane + 64 < d, a2 = lane + 128 < d;
  if (a0) { c0 = cols[lane];       float x = w1 + Wh2[c0]; e0 = x > 0.0f ? x : LRALPHA * x; }
  if (a1) { c1 = cols[lane + 64];  float x = w1 + Wh2[c1]; e1 = x > 0.0f ? x : LRALPHA * x; }
  if (a2) { c2 = cols[lane + 128]; float x = w1 + Wh2[c2]; e2 = x > 0.0f ? x : LRALPHA * x; }
  float mx = fmaxf(e0, fmaxf(e1, e2));
  for (int o = 32; o > 0; o >>= 1) mx = fmaxf(mx, __shfl_xor(mx, o));
  const float x0 = a0 ? expf(e0 - mx) : 0.0f;
  const float x1 = a1 ? expf(e1 - mx) : 0.0f;
  const float x2 = a2 ? expf(e2 - mx) : 0.0f;
  float sum = x0 + x1 + x2;
  for (int o = 32; o > 0; o >>= 1) sum += __shfl_xor(sum, o);
  const float Z = (d > 0) ? sum : 1.0f;
  const float invZ = 1.0f / Z;
  if (a0) att[rowbase + lane] = x0 * invZ;
  if (a1) att[rowbase + lane + 64] = x1 * invZ;
  if (a2) att[rowbase + lane + 128] = x2 * invZ;
  int b[7] = {0, 0, 0, 0, 0, 0, 0};
#pragma unroll
  for (int m = 1; m <= 7; ++m) {
    b[m - 1] = (int)__popcll(__ballot(a0 && c0 < m * 1024)) +
               (int)__popcll(__ballot(a1 && c1 < m * 1024)) +
               (int)__popcll(__ballot(a2 && c2 < m * 1024));
  }
  if (lane == 0) {
    mrow[row] = mx;
    Zrow[row] = Z;
    short* q = qb8 + (size_t)row * 8;
    q[0] = (short)b[0]; q[1] = (short)b[1]; q[2] = (short)b[2]; q[3] = (short)b[3];
    q[4] = (short)b[4]; q[5] = (short)b[5]; q[6] = (short)b[6]; q[7] = (short)d;
  }
}

// ---------------------------------------------------------------------------
// Kernel D2: packed transpose-edge values only.
// edgesT[row][t] = (j, att[j,row]) via closed form from neighbor j's stats.
// ---------------------------------------------------------------------------
__global__ void __launch_bounds__(256) k_att(
    const int* __restrict__ nbr, const int* __restrict__ deg,
    const float* __restrict__ Wh1, const float* __restrict__ Wh2,
    const float* __restrict__ mrow, const float* __restrict__ Zrow,
    int2* __restrict__ edgesT) {
  const int wave = threadIdx.x >> 6;
  const int lane = threadIdx.x & 63;
  const int row = blockIdx.x * 4 + wave;
  const int d = deg[row];
  const size_t rowbase = (size_t)row * MAXD;
  const int* cols = nbr + rowbase;
  const float w2r = Wh2[row];
  for (int t = lane; t < d; t += 64) {
    const int j = cols[t];
    float e2 = Wh1[j] + w2r;
    e2 = e2 > 0.0f ? e2 : LRALPHA * e2;
    const float v = expf(e2 - mrow[j]) / Zrow[j];
    edgesT[rowbase + t] = make_int2(j, __float_as_int(v));
  }
}

// ---------------------------------------------------------------------------
// Kernel E (R6 best-measured form): per row i, 512 threads (8 waves), comb in
// LDS. Octant-partitioned scatter with 8-lane group expansion; LDS atomicAdd
// (wave-internal HW lane order -> replay-deterministic). Then 4-pass radix
// select of the s2-th largest (zeros skipped) and binary row emit, nt stores.
// ---------------------------------------------------------------------------
__global__ void __launch_bounds__(512) k_twostep(
    const int* __restrict__ nbr, const int* __restrict__ deg,
    const int* __restrict__ s2v, const float* __restrict__ att,
    const int2* __restrict__ edgesT, const short* __restrict__ qb8,
    float* __restrict__ out1) {
  __shared__ float comb[NN];
  __shared__ float wvals[MAXD];
  __shared__ int kcols[MAXD];
  __shared__ short sqb[MAXD][8];
  __shared__ unsigned int hist[256];
  __shared__ unsigned int shPrefix;
  __shared__ int shRemaining;
  const int tid = threadIdx.x;
  const int wave = tid >> 6;
  const int lane = tid & 63;
  const int row = blockIdx.x;
  const f32x4 z4 = {0.0f, 0.0f, 0.0f, 0.0f};
  for (int j = tid * 4; j < NN; j += 2048)
    *reinterpret_cast<f32x4*>(&comb[j]) = z4;
  const int d = deg[row];
  const int* cols = nbr + (size_t)row * MAXD;
  const float* arow = att + (size_t)row * MAXD;
  for (int t = tid; t < d; t += 512) {
    const int c = cols[t];
    kcols[t] = c;
    wvals[t] = arow[t];
    *reinterpret_cast<int4*>(&sqb[t][0]) =
        *reinterpret_cast<const int4*>(&qb8[(size_t)c * 8]);
  }
  __syncthreads();
  // --- group-expanded scatter: 8 groups x 8 lanes per wave
  {
    const int grp = lane >> 3;   // 0..7: which neighbor within the batch
    const int sub = lane & 7;    // 0..7: offset within the segment
    for (int t0 = 0; t0 < d; t0 += 8) {
      const int t = t0 + grp;
      if (t < d) {
        const int qs = wave ? (int)sqb[t][wave - 1] : 0;
        const int qe = (int)sqb[t][wave];
        const float w = wvals[t];
        const int2* ek = edgesT + (size_t)kcols[t] * MAXD;
        for (int off = qs + sub; off < qe; off += 8) {
          const int2 e = ek[off];
          atomicAdd(&comb[e.x], w * __int_as_float(e.y));
        }
      }
    }
  }
  // --- add row's own attention values (wave's own octant segment)
  {
    const short* qr = qb8 + (size_t)row * 8;
    const int qlo = wave ? (int)qr[wave - 1] : 0;
    const int qhi = (int)qr[wave];
    for (int t = qlo + lane; t < qhi; t += 64) comb[kcols[t]] += wvals[t];
  }
  __syncthreads();
  if (tid == 0) comb[row] = 0.0f;
  __syncthreads();
  const int kk = s2v[row];
  const size_t obase = (size_t)row * NN;
  if (kk <= 0) {
    for (int j = tid * 4; j < NN; j += 2048)
      __builtin_nontemporal_store(z4, reinterpret_cast<f32x4*>(&out1[obase + j]));
    return;
  }
  // --- radix select: kk-th largest of comb. All values >= 0 -> uint order.
  // Threshold provably > 0, so zero entries are skipped.
  unsigned int prefix = 0u;
  int remaining = kk;
  for (int pass = 0; pass < 4; ++pass) {
    const int shift = 24 - 8 * pass;
    const unsigned int pmask = (pass == 0) ? 0u : (0xFFFFFFFFu << (shift + 8));
    if (tid < 256) hist[tid] = 0u;
    __syncthreads();
    for (int j = tid * 4; j < NN; j += 2048) {
      const f32x4 cv = *reinterpret_cast<const f32x4*>(&comb[j]);
#pragma unroll
      for (int q = 0; q < 4; ++q) {
        const unsigned int u = __float_as_uint(cv[q]);
        if (u != 0u && (u & pmask) == prefix)
          atomicAdd(&hist[(u >> shift) & 255u], 1u);
      }
    }
    __syncthreads();
    if (tid < 64) {
      const int bHi = 255 - 4 * lane;  // lane 0 owns highest bins
      const unsigned int c0 = hist[bHi];
      const unsigned int c1 = hist[bHi - 1];
      const unsigned int c2 = hist[bHi - 2];
      const unsigned int c3 = hist[bHi - 3];
      const unsigned int gs = c0 + c1 + c2 + c3;
      unsigned int run2 = gs;
      for (int o = 1; o < 64; o <<= 1) {
        const unsigned int tt = __shfl_up(run2, o);
        if (lane >= o) run2 += tt;
      }
      const unsigned int pre = run2 - gs;  // count in strictly higher bins
      const unsigned int rem = (unsigned int)remaining;
      if (pre < rem && pre + gs >= rem) {  // exactly one lane hits
        unsigned int above;
        int digit;
        if (pre + c0 >= rem) { digit = bHi; above = pre; }
        else if (pre + c0 + c1 >= rem) { digit = bHi - 1; above = pre + c0; }
        else if (pre + c0 + c1 + c2 >= rem) { digit = bHi - 2; above = pre + c0 + c1; }
        else { digit = bHi - 3; above = pre + c0 + c1 + c2; }
        shPrefix = prefix | ((unsigned int)digit << shift);
        shRemaining = remaining - (int)above;
      }
    }
    __syncthreads();
    prefix = shPrefix;
    remaining = shRemaining;
    __syncthreads();
  }
  const float thr = __uint_as_float(prefix);  // exact kk-th largest value
  for (int j = tid * 4; j < NN; j += 2048) {
    const f32x4 cv = *reinterpret_cast<const f32x4*>(&comb[j]);
    f32x4 ov;
    ov[0] = (cv[0] >= thr && cv[0] > 0.0f) ? 1.0f : 0.0f;
    ov[1] = (cv[1] >= thr && cv[1] > 0.0f) ? 1.0f : 0.0f;
    ov[2] = (cv[2] >= thr && cv[2] > 0.0f) ? 1.0f : 0.0f;
    ov[3] = (cv[3] >= thr && cv[3] > 0.0f) ? 1.0f : 0.0f;
    __builtin_nontemporal_store(ov, reinterpret_cast<f32x4*>(&out1[obase + j]));
  }
}

// ---------------------------------------------------------------------------
// Kernel F: h_prime = attention @ Wh (sparse x dense), then ELU.
// ---------------------------------------------------------------------------
__global__ void __launch_bounds__(256) k_hprime(
    const int* __restrict__ nbr, const int* __restrict__ deg,
    const float* __restrict__ att, const float* __restrict__ Wh,
    float* __restrict__ out0) {
  __shared__ int scol[MAXD];
  __shared__ float sval[MAXD];
  const int row = blockIdx.x;
  const int c = threadIdx.x;
  const int d = deg[row];
  const int* cols = nbr + (size_t)row * MAXD;
  const float* arow = att + (size_t)row * MAXD;
  for (int t = threadIdx.x; t < d; t += 256) {
    scol[t] = cols[t];
    sval[t] = arow[t];
  }
  __syncthreads();
  float a0 = 0.0f, a1 = 0.0f, a2 = 0.0f, a3 = 0.0f;
  int t = 0;
  for (; t + 4 <= d; t += 4) {
    a0 += sval[t + 0] * Wh[(size_t)scol[t + 0] * KFOUT + c];
    a1 += sval[t + 1] * Wh[(size_t)scol[t + 1] * KFOUT + c];
    a2 += sval[t + 2] * Wh[(size_t)scol[t + 2] * KFOUT + c];
    a3 += sval[t + 3] * Wh[(size_t)scol[t + 3] * KFOUT + c];
  }
  for (; t < d; ++t) a0 += sval[t] * Wh[(size_t)scol[t] * KFOUT + c];
  const float acc = (a0 + a1) + (a2 + a3);
  out0[(size_t)row * KFOUT + c] = acc > 0.0f ? acc : expm1f(acc);
}

extern "C" void kernel_launch(void* const* d_in, const int* in_sizes, int n_in,
                              void* d_out, int out_size, void* d_ws, size_t ws_size,
                              hipStream_t stream) {
  const float* h = (const float*)d_in[0];
  const float* adj = (const float*)d_in[1];
  const float* W = (const float*)d_in[2];
  const float* a = (const float*)d_in[3];

  float* out0 = (float*)d_out;                  // [8192, 256] elu(h_prime)
  float* out1 = out0 + (size_t)NN * KFOUT;      // [8192, 8192] adj_resize

  // workspace layout (~33.9 MB)
  float* Wh = (float*)d_ws;                        // 8192*256
  float* Wh1 = Wh + (size_t)NN * KFOUT;            // 8192
  float* Wh2 = Wh1 + NN;                           // 8192
  float* mrow = Wh2 + NN;                          // 8192
  float* Zrow = mrow + NN;                         // 8192
  float* att = Zrow + NN;                          // 8192*MAXD
  float* edgesF = att + (size_t)NN * MAXD;         // 8192*MAXD int2
  int2* edgesT = (int2*)edgesF;
  int* nbr = (int*)(edgesF + (size_t)NN * MAXD * 2);  // 8192*MAXD
  int* deg = nbr + (size_t)NN * MAXD;              // 8192
  int* s2v = deg + NN;                             // 8192
  short* qb8 = (short*)(s2v + NN);                 // 8192*8 shorts (128 KB)

  k_build_csr<<<NN / 4, 256, 0, stream>>>(adj, nbr, deg, s2v);
  dim3 ggrid(KFOUT / 64, NN / 64);
  k_gemm<<<ggrid, 256, 0, stream>>>(h, W, Wh);
  k_rowdots<<<NN, 256, 0, stream>>>(Wh, a, Wh1, Wh2);
  k_stats<<<NN / 4, 256, 0, stream>>>(nbr, deg, Wh1, Wh2, mrow, Zrow, att, qb8);
  k_att<<<NN / 4, 256, 0, stream>>>(nbr, deg, Wh1, Wh2, mrow, Zrow, edgesT);
  k_twostep<<<NN, 512, 0, stream>>>(nbr, deg, s2v, att, edgesT, qb8, out1);
  k_hprime<<<NN, 256, 0, stream>>>(nbr, deg, att, Wh, out0);
}

// Round 12
// 474.487 us; speedup vs baseline: 1.3655x; 1.0159x over previous
//
#include <hip/hip_runtime.h>
#include <cstdint>
#include <cstddef>

#define NN 8192
#define KFIN 1024
#define KFOUT 256
#define MAXD 192
#define LRALPHA 0.2f

typedef float f32x4 __attribute__((ext_vector_type(4)));

// ---------------------------------------------------------------------------
// Kernel A: dense adj -> CSR neighbor lists (stable ascending-column order via
// 4x ballot on float4 nontemporal loads), degree, s2 = off-diagonal degree.
// ---------------------------------------------------------------------------
__global__ void __launch_bounds__(256) k_build_csr(
    const float* __restrict__ adj, int* __restrict__ nbr,
    int* __restrict__ deg, int* __restrict__ s2v) {
  const int wave = threadIdx.x >> 6;
  const int lane = threadIdx.x & 63;
  const int row = blockIdx.x * 4 + wave;
  const float* arow = adj + (size_t)row * NN;
  int* outp = nbr + (size_t)row * MAXD;
  int count = 0;
  int dflag = 0;
  const unsigned long long below = (1ull << lane) - 1ull;
  for (int c0 = 0; c0 < NN; c0 += 256) {
    const int c = c0 + lane * 4;
    const f32x4 v = __builtin_nontemporal_load(
        reinterpret_cast<const f32x4*>(arow + c));
    const unsigned long long m0 = __ballot(v[0] > 0.0f);
    const unsigned long long m1 = __ballot(v[1] > 0.0f);
    const unsigned long long m2 = __ballot(v[2] > 0.0f);
    const unsigned long long m3 = __ballot(v[3] > 0.0f);
    int pos = count + (int)(__popcll(m0 & below) + __popcll(m1 & below) +
                            __popcll(m2 & below) + __popcll(m3 & below));
    if (v[0] > 0.0f) { if (pos < MAXD) outp[pos] = c + 0; ++pos; if (c + 0 == row) dflag = 1; }
    if (v[1] > 0.0f) { if (pos < MAXD) outp[pos] = c + 1; ++pos; if (c + 1 == row) dflag = 1; }
    if (v[2] > 0.0f) { if (pos < MAXD) outp[pos] = c + 2; ++pos; if (c + 2 == row) dflag = 1; }
    if (v[3] > 0.0f) { if (pos < MAXD) outp[pos] = c + 3; ++pos; if (c + 3 == row) dflag = 1; }
    count += (int)(__popcll(m0) + __popcll(m1) + __popcll(m2) + __popcll(m3));
  }
  const int anyd = __any(dflag) ? 1 : 0;
  if (lane == 0) {
    deg[row] = count < MAXD ? count : MAXD;
    s2v[row] = count - anyd;
  }
}

// ---------------------------------------------------------------------------
// Kernel B: Wh = h @ W, f32 tiled GEMM (64x64 tile, 4x4 per thread, BK=32).
// ---------------------------------------------------------------------------
__global__ void __launch_bounds__(256) k_gemm(
    const float* __restrict__ A, const float* __restrict__ B,
    float* __restrict__ C) {
  __shared__ float As[32][65];
  __shared__ float Bs[32][65];
  const int tid = threadIdx.x;
  const int brow = blockIdx.y * 64;
  const int bcol = blockIdx.x * 64;
  const int tx = tid & 15;
  const int ty = tid >> 4;
  float acc[4][4];
#pragma unroll
  for (int i = 0; i < 4; ++i)
#pragma unroll
    for (int j = 0; j < 4; ++j) acc[i][j] = 0.0f;
  const int ar = tid >> 2;
  const int ac = (tid & 3) << 2;
  const int br = tid >> 4;
  const int bc = (tid & 15) << 2;
  for (int k0 = 0; k0 < KFIN; k0 += 32) {
    const float4 av0 =
        *reinterpret_cast<const float4*>(A + (size_t)(brow + ar) * KFIN + k0 + ac);
    const float4 av1 =
        *reinterpret_cast<const float4*>(A + (size_t)(brow + ar) * KFIN + k0 + 16 + ac);
    const float4 bv0 =
        *reinterpret_cast<const float4*>(B + (size_t)(k0 + br) * KFOUT + bcol + bc);
    const float4 bv1 =
        *reinterpret_cast<const float4*>(B + (size_t)(k0 + 16 + br) * KFOUT + bcol + bc);
    As[ac + 0][ar] = av0.x;
    As[ac + 1][ar] = av0.y;
    As[ac + 2][ar] = av0.z;
    As[ac + 3][ar] = av0.w;
    As[16 + ac + 0][ar] = av1.x;
    As[16 + ac + 1][ar] = av1.y;
    As[16 + ac + 2][ar] = av1.z;
    As[16 + ac + 3][ar] = av1.w;
    Bs[br][bc + 0] = bv0.x;
    Bs[br][bc + 1] = bv0.y;
    Bs[br][bc + 2] = bv0.z;
    Bs[br][bc + 3] = bv0.w;
    Bs[16 + br][bc + 0] = bv1.x;
    Bs[16 + br][bc + 1] = bv1.y;
    Bs[16 + br][bc + 2] = bv1.z;
    Bs[16 + br][bc + 3] = bv1.w;
    __syncthreads();
#pragma unroll
    for (int kk = 0; kk < 32; ++kk) {
      const float a0 = As[kk][ty * 4 + 0];
      const float a1 = As[kk][ty * 4 + 1];
      const float a2 = As[kk][ty * 4 + 2];
      const float a3 = As[kk][ty * 4 + 3];
      const float b0 = Bs[kk][tx * 4 + 0];
      const float b1 = Bs[kk][tx * 4 + 1];
      const float b2 = Bs[kk][tx * 4 + 2];
      const float b3 = Bs[kk][tx * 4 + 3];
      acc[0][0] += a0 * b0; acc[0][1] += a0 * b1; acc[0][2] += a0 * b2; acc[0][3] += a0 * b3;
      acc[1][0] += a1 * b0; acc[1][1] += a1 * b1; acc[1][2] += a1 * b2; acc[1][3] += a1 * b3;
      acc[2][0] += a2 * b0; acc[2][1] += a2 * b1; acc[2][2] += a2 * b2; acc[2][3] += a2 * b3;
      acc[3][0] += a3 * b0; acc[3][1] += a3 * b1; acc[3][2] += a3 * b2; acc[3][3] += a3 * b3;
    }
    __syncthreads();
  }
#pragma unroll
  for (int i = 0; i < 4; ++i) {
#pragma unroll
    for (int j = 0; j < 4; ++j) {
      C[(size_t)(brow + ty * 4 + i) * KFOUT + bcol + tx * 4 + j] = acc[i][j];
    }
  }
}

// ---------------------------------------------------------------------------
// Kernel C: Wh1 = Wh @ a[:256], Wh2 = Wh @ a[256:], one block per row.
// ---------------------------------------------------------------------------
__global__ void __launch_bounds__(256) k_rowdots(
    const float* __restrict__ Wh, const float* __restrict__ a,
    float* __restrict__ Wh1, float* __restrict__ Wh2) {
  __shared__ float sA[256];
  __shared__ float sB[256];
  const int row = blockIdx.x;
  const int t = threadIdx.x;
  const float w = Wh[(size_t)row * KFOUT + t];
  sA[t] = w * a[t];
  sB[t] = w * a[KFOUT + t];
  __syncthreads();
  for (int s = 128; s > 0; s >>= 1) {
    if (t < s) {
      sA[t] += sA[t + s];
      sB[t] += sB[t + s];
    }
    __syncthreads();
  }
  if (t == 0) {
    Wh1[row] = sA[0];
    Wh2[row] = sB[0];
  }
}

// ---------------------------------------------------------------------------
// Kernel D1: per-row softmax stats (m, Z) + row-normalized attention values
// + octant split counts qb8 -- all from ONE edge gather.
// ---------------------------------------------------------------------------
__global__ void __launch_bounds__(256) k_stats(
    const int* __restrict__ nbr, const int* __restrict__ deg,
    const float* __restrict__ Wh1, const float* __restrict__ Wh2,
    float* __restrict__ mrow, float* __restrict__ Zrow,
    float* __restrict__ att, short* __restrict__ qb8) {
  const int wave = threadIdx.x >> 6;
  const int lane = threadIdx.x & 63;
  const int row = blockIdx.x * 4 + wave;
  const int d = deg[row];
  const size_t rowbase = (size_t)row * MAXD;
  const int* cols = nbr + rowbase;
  const float w1 = Wh1[row];
  int c0 = 0x7fffffff, c1 = 0x7fffffff, c2 = 0x7fffffff;
  float e0 = -1e30f, e1 = -1e30f, e2 = -1e30f;
  const bool a0 = lane < d, a1 = lane + 64 < d, a2 = lane + 128 < d;
  if (a0) { c0 = cols[lane];       float x = w1 + Wh2[c0]; e0 = x > 0.0f ? x : LRALPHA * x; }
  if (a1) { c1 = cols[lane + 64];  float x = w1 + Wh2[c1]; e1 = x > 0.0f ? x : LRALPHA * x; }
  if (a2) { c2 = cols[lane + 128]; float x = w1 + Wh2[c2]; e2 = x > 0.0f ? x : LRALPHA * x; }
  float mx = fmaxf(e0, fmaxf(e1, e2));
  for (int o = 32; o > 0; o >>= 1) mx = fmaxf(mx, __shfl_xor(mx, o));
  const float x0 = a0 ? expf(e0 - mx) : 0.0f;
  const float x1 = a1 ? expf(e1 - mx) : 0.0f;
  const float x2 = a2 ? expf(e2 - mx) : 0.0f;
  float sum = x0 + x1 + x2;
  for (int o = 32; o > 0; o >>= 1) sum += __shfl_xor(sum, o);
  const float Z = (d > 0) ? sum : 1.0f;
  const float invZ = 1.0f / Z;
  if (a0) att[rowbase + lane] = x0 * invZ;
  if (a1) att[rowbase + lane + 64] = x1 * invZ;
  if (a2) att[rowbase + lane + 128] = x2 * invZ;
  int b[7] = {0, 0, 0, 0, 0, 0, 0};
#pragma unroll
  for (int m = 1; m <= 7; ++m) {
    b[m - 1] = (int)__popcll(__ballot(a0 && c0 < m * 1024)) +
               (int)__popcll(__ballot(a1 && c1 < m * 1024)) +
               (int)__popcll(__ballot(a2 && c2 < m * 1024));
  }
  if (lane == 0) {
    mrow[row] = mx;
    Zrow[row] = Z;
    short* q = qb8 + (size_t)row * 8;
    q[0] = (short)b[0]; q[1] = (short)b[1]; q[2] = (short)b[2]; q[3] = (short)b[3];
    q[4] = (short)b[4]; q[5] = (short)b[5]; q[6] = (short)b[6]; q[7] = (short)d;
  }
}

// ---------------------------------------------------------------------------
// Kernel D2: packed transpose-edge values only.
// ---------------------------------------------------------------------------
__global__ void __launch_bounds__(256) k_att(
    const int* __restrict__ nbr, const int* __restrict__ deg,
    const float* __restrict__ Wh1, const float* __restrict__ Wh2,
    const float* __restrict__ mrow, const float* __restrict__ Zrow,
    int2* __restrict__ edgesT) {
  const int wave = threadIdx.x >> 6;
  const int lane = threadIdx.x & 63;
  const int row = blockIdx.x * 4 + wave;
  const int d = deg[row];
  const size_t rowbase = (size_t)row * MAXD;
  const int* cols = nbr + rowbase;
  const float w2r = Wh2[row];
  for (int t = lane; t < d; t += 64) {
    const int j = cols[t];
    float e2 = Wh1[j] + w2r;
    e2 = e2 > 0.0f ? e2 : LRALPHA * e2;
    const float v = expf(e2 - mrow[j]) / Zrow[j];
    edgesT[rowbase + t] = make_int2(j, __float_as_int(v));
  }
}

// ---------------------------------------------------------------------------
// Kernel E: per row i, 512 threads (8 waves), comb row in LDS.
// R6 scatter (octant-partitioned 8-lane group expansion) kept verbatim.
// Select: pass 0 = dense 8-bit radix (as before) -> COMPACT the chosen bin's
// candidates (~100-400 values, order-independent multiset) into LDS ->
// passes 1-3 run on the compact array (1 value/thread, ~2 LDS instrs/wave
// instead of ~32). Cuts dense comb sweeps 5->3 and hist atomics ~70%.
// Dense fallback if candidates > 512.
// ---------------------------------------------------------------------------
__global__ void __launch_bounds__(512) k_twostep(
    const int* __restrict__ nbr, const int* __restrict__ deg,
    const int* __restrict__ s2v, const float* __restrict__ att,
    const int2* __restrict__ edgesT, const short* __restrict__ qb8,
    float* __restrict__ out1) {
  __shared__ float comb[NN];                 // 32768 B
  __shared__ float wvals[MAXD];              //   768 B
  __shared__ unsigned short kcols[MAXD];     //   384 B
  __shared__ short sqb[MAXD][8];             //  3072 B
  __shared__ unsigned int hist[256];         //  1024 B
  __shared__ unsigned int scomp[512];        //  2048 B
  __shared__ unsigned int shPrefix;
  __shared__ int shRemaining;
  __shared__ int shNc;
  const int tid = threadIdx.x;
  const int wave = tid >> 6;
  const int lane = tid & 63;
  const int row = blockIdx.x;
  const f32x4 z4 = {0.0f, 0.0f, 0.0f, 0.0f};
  for (int j = tid * 4; j < NN; j += 2048)
    *reinterpret_cast<f32x4*>(&comb[j]) = z4;
  const int d = deg[row];
  const int* cols = nbr + (size_t)row * MAXD;
  const float* arow = att + (size_t)row * MAXD;
  for (int t = tid; t < d; t += 512) {
    const int c = cols[t];
    kcols[t] = (unsigned short)c;
    wvals[t] = arow[t];
    *reinterpret_cast<int4*>(&sqb[t][0]) =
        *reinterpret_cast<const int4*>(&qb8[(size_t)c * 8]);
  }
  if (tid == 0) shNc = 0;
  __syncthreads();
  // --- group-expanded scatter: 8 groups x 8 lanes per wave (R6 form)
  {
    const int grp = lane >> 3;   // 0..7: which neighbor within the batch
    const int sub = lane & 7;    // 0..7: offset within the segment
    for (int t0 = 0; t0 < d; t0 += 8) {
      const int t = t0 + grp;
      if (t < d) {
        const int qs = wave ? (int)sqb[t][wave - 1] : 0;
        const int qe = (int)sqb[t][wave];
        const float w = wvals[t];
        const int2* ek = edgesT + (size_t)kcols[t] * MAXD;
        for (int off = qs + sub; off < qe; off += 8) {
          const int2 e = ek[off];
          atomicAdd(&comb[e.x], w * __int_as_float(e.y));
        }
      }
    }
  }
  // --- add row's own attention values (wave's own octant segment)
  {
    const short* qr = qb8 + (size_t)row * 8;
    const int qlo = wave ? (int)qr[wave - 1] : 0;
    const int qhi = (int)qr[wave];
    for (int t = qlo + lane; t < qhi; t += 64) comb[(int)kcols[t]] += wvals[t];
  }
  __syncthreads();
  if (tid == 0) comb[row] = 0.0f;
  __syncthreads();
  const int kk = s2v[row];
  const size_t obase = (size_t)row * NN;
  if (kk <= 0) {
    for (int j = tid * 4; j < NN; j += 2048)
      __builtin_nontemporal_store(z4, reinterpret_cast<f32x4*>(&out1[obase + j]));
    return;
  }
  // --- pass 0: dense 8-bit radix over comb (zeros skipped; threshold > 0)
  if (tid < 256) hist[tid] = 0u;
  __syncthreads();
  for (int j = tid * 4; j < NN; j += 2048) {
    const f32x4 cv = *reinterpret_cast<const f32x4*>(&comb[j]);
#pragma unroll
    for (int q = 0; q < 4; ++q) {
      const unsigned int u = __float_as_uint(cv[q]);
      if (u != 0u) atomicAdd(&hist[u >> 24], 1u);
    }
  }
  __syncthreads();
  if (tid < 64) {
    const int bHi = 255 - 4 * lane;  // lane 0 owns highest bins
    const unsigned int c0 = hist[bHi];
    const unsigned int c1 = hist[bHi - 1];
    const unsigned int c2 = hist[bHi - 2];
    const unsigned int c3 = hist[bHi - 3];
    const unsigned int gs = c0 + c1 + c2 + c3;
    unsigned int run2 = gs;
    for (int o = 1; o < 64; o <<= 1) {
      const unsigned int tt = __shfl_up(run2, o);
      if (lane >= o) run2 += tt;
    }
    const unsigned int pre = run2 - gs;
    const unsigned int rem = (unsigned int)kk;
    if (pre < rem && pre + gs >= rem) {
      unsigned int above;
      int digit;
      if (pre + c0 >= rem) { digit = bHi; above = pre; }
      else if (pre + c0 + c1 >= rem) { digit = bHi - 1; above = pre + c0; }
      else if (pre + c0 + c1 + c2 >= rem) { digit = bHi - 2; above = pre + c0 + c1; }
      else { digit = bHi - 3; above = pre + c0 + c1 + c2; }
      shPrefix = (unsigned)digit << 24;
      shRemaining = kk - (int)above;
    }
  }
  __syncthreads();
  unsigned int prefix = shPrefix;
  int remaining = shRemaining;
  const unsigned int digit0 = prefix >> 24;
  __syncthreads();
  // --- compact the chosen bin's candidates (order-independent multiset)
  for (int j = tid * 4; j < NN; j += 2048) {
    const f32x4 cv = *reinterpret_cast<const f32x4*>(&comb[j]);
#pragma unroll
    for (int q = 0; q < 4; ++q) {
      const unsigned int u = __float_as_uint(cv[q]);
      if (u != 0u && (u >> 24) == digit0) {
        const int idx = atomicAdd(&shNc, 1);
        if (idx < 512) scomp[idx] = u;
      }
    }
  }
  __syncthreads();
  const int nc = shNc;
  const bool densefb = nc > 512;  // rare fallback
  const unsigned int myu = (!densefb && tid < nc) ? scomp[tid] : 0u;
  // --- passes 1-3: on compact array (or dense comb if fallback)
  for (int pass = 1; pass < 4; ++pass) {
    const int shift = 24 - 8 * pass;
    const unsigned int pmask = 0xFFFFFFFFu << (shift + 8);
    if (tid < 256) hist[tid] = 0u;
    __syncthreads();
    if (!densefb) {
      if (tid < nc && (myu & pmask) == prefix)
        atomicAdd(&hist[(myu >> shift) & 255u], 1u);
    } else {
      for (int j = tid * 4; j < NN; j += 2048) {
        const f32x4 cv = *reinterpret_cast<const f32x4*>(&comb[j]);
#pragma unroll
        for (int q = 0; q < 4; ++q) {
          const unsigned int u = __float_as_uint(cv[q]);
          if (u != 0u && (u & pmask) == prefix)
            atomicAdd(&hist[(u >> shift) & 255u], 1u);
        }
      }
    }
    __syncthreads();
    if (tid < 64) {
      const int bHi = 255 - 4 * lane;
      const unsigned int c0 = hist[bHi];
      const unsigned int c1 = hist[bHi - 1];
      const unsigned int c2 = hist[bHi - 2];
      const unsigned int c3 = hist[bHi - 3];
      const unsigned int gs = c0 + c1 + c2 + c3;
      unsigned int run2 = gs;
      for (int o = 1; o < 64; o <<= 1) {
        const unsigned int tt = __shfl_up(run2, o);
        if (lane >= o) run2 += tt;
      }
      const unsigned int pre = run2 - gs;
      const unsigned int rem = (unsigned int)remaining;
      if (pre < rem && pre + gs >= rem) {
        unsigned int above;
        int digit;
        if (pre + c0 >= rem) { digit = bHi; above = pre; }
        else if (pre + c0 + c1 >= rem) { digit = bHi - 1; above = pre + c0; }
        else if (pre + c0 + c1 + c2 >= rem) { digit = bHi - 2; above = pre + c0 + c1; }
        else { digit = bHi - 3; above = pre + c0 + c1 + c2; }
        shPrefix = prefix | ((unsigned int)digit << shift);
        shRemaining = remaining - (int)above;
      }
    }
    __syncthreads();
    prefix = shPrefix;
    remaining = shRemaining;
    __syncthreads();
  }
  const float thr = __uint_as_float(prefix);  // exact kk-th largest value
  for (int j = tid * 4; j < NN; j += 2048) {
    const f32x4 cv = *reinterpret_cast<const f32x4*>(&comb[j]);
    f32x4 ov;
    ov[0] = (cv[0] >= thr && cv[0] > 0.0f) ? 1.0f : 0.0f;
    ov[1] = (cv[1] >= thr && cv[1] > 0.0f) ? 1.0f : 0.0f;
    ov[2] = (cv[2] >= thr && cv[2] > 0.0f) ? 1.0f : 0.0f;
    ov[3] = (cv[3] >= thr && cv[3] > 0.0f) ? 1.0f : 0.0f;
    __builtin_nontemporal_store(ov, reinterpret_cast<f32x4*>(&out1[obase + j]));
  }
}

// ---------------------------------------------------------------------------
// Kernel F: h_prime = attention @ Wh (sparse x dense), then ELU.
// ---------------------------------------------------------------------------
__global__ void __launch_bounds__(256) k_hprime(
    const int* __restrict__ nbr, const int* __restrict__ deg,
    const float* __restrict__ att, const float* __restrict__ Wh,
    float* __restrict__ out0) {
  __shared__ int scol[MAXD];
  __shared__ float sval[MAXD];
  const int row = blockIdx.x;
  const int c = threadIdx.x;
  const int d = deg[row];
  const int* cols = nbr + (size_t)row * MAXD;
  const float* arow = att + (size_t)row * MAXD;
  for (int t = threadIdx.x; t < d; t += 256) {
    scol[t] = cols[t];
    sval[t] = arow[t];
  }
  __syncthreads();
  float a0 = 0.0f, a1 = 0.0f, a2 = 0.0f, a3 = 0.0f;
  int t = 0;
  for (; t + 4 <= d; t += 4) {
    a0 += sval[t + 0] * Wh[(size_t)scol[t + 0] * KFOUT + c];
    a1 += sval[t + 1] * Wh[(size_t)scol[t + 1] * KFOUT + c];
    a2 += sval[t + 2] * Wh[(size_t)scol[t + 2] * KFOUT + c];
    a3 += sval[t + 3] * Wh[(size_t)scol[t + 3] * KFOUT + c];
  }
  for (; t < d; ++t) a0 += sval[t] * Wh[(size_t)scol[t] * KFOUT + c];
  const float acc = (a0 + a1) + (a2 + a3);
  out0[(size_t)row * KFOUT + c] = acc > 0.0f ? acc : expm1f(acc);
}

extern "C" void kernel_launch(void* const* d_in, const int* in_sizes, int n_in,
                              void* d_out, int out_size, void* d_ws, size_t ws_size,
                              hipStream_t stream) {
  const float* h = (const float*)d_in[0];
  const float* adj = (const float*)d_in[1];
  const float* W = (const float*)d_in[2];
  const float* a = (const float*)d_in[3];

  float* out0 = (float*)d_out;                  // [8192, 256] elu(h_prime)
  float* out1 = out0 + (size_t)NN * KFOUT;      // [8192, 8192] adj_resize

  // workspace layout (~33.9 MB)
  float* Wh = (float*)d_ws;                        // 8192*256
  float* Wh1 = Wh + (size_t)NN * KFOUT;            // 8192
  float* Wh2 = Wh1 + NN;                           // 8192
  float* mrow = Wh2 + NN;                          // 8192
  float* Zrow = mrow + NN;                         // 8192
  float* att = Zrow + NN;                          // 8192*MAXD
  float* edgesF = att + (size_t)NN * MAXD;         // 8192*MAXD int2
  int2* edgesT = (int2*)edgesF;
  int* nbr = (int*)(edgesF + (size_t)NN * MAXD * 2);  // 8192*MAXD
  int* deg = nbr + (size_t)NN * MAXD;              // 8192
  int* s2v = deg + NN;                             // 8192
  short* qb8 = (short*)(s2v + NN);                 // 8192*8 shorts (128 KB)

  k_build_csr<<<NN / 4, 256, 0, stream>>>(adj, nbr, deg, s2v);
  dim3 ggrid(KFOUT / 64, NN / 64);
  k_gemm<<<ggrid, 256, 0, stream>>>(h, W, Wh);
  k_rowdots<<<NN, 256, 0, stream>>>(Wh, a, Wh1, Wh2);
  k_stats<<<NN / 4, 256, 0, stream>>>(nbr, deg, Wh1, Wh2, mrow, Zrow, att, qb8);
  k_att<<<NN / 4, 256, 0, stream>>>(nbr, deg, Wh1, Wh2, mrow, Zrow, edgesT);
  k_twostep<<<NN, 512, 0, stream>>>(nbr, deg, s2v, att, edgesT, qb8, out1);
  k_hprime<<<NN, 256, 0, stream>>>(nbr, deg, att, Wh, out0);
}

// Round 13
// 462.390 us; speedup vs baseline: 1.4012x; 1.0262x over previous
//
#include <hip/hip_runtime.h>
#include <cstdint>
#include <cstddef>

#define NN 8192
#define KFIN 1024
#define KFOUT 256
#define MAXD 192
#define LRALPHA 0.2f

typedef float f32x4 __attribute__((ext_vector_type(4)));

// ---------------------------------------------------------------------------
// Kernel A: dense adj -> CSR neighbor lists (stable ascending-column order via
// 4x ballot on float4 nontemporal loads), degree, s2 = off-diagonal degree.
// ---------------------------------------------------------------------------
__global__ void __launch_bounds__(256) k_build_csr(
    const float* __restrict__ adj, int* __restrict__ nbr,
    int* __restrict__ deg, int* __restrict__ s2v) {
  const int wave = threadIdx.x >> 6;
  const int lane = threadIdx.x & 63;
  const int row = blockIdx.x * 4 + wave;
  const float* arow = adj + (size_t)row * NN;
  int* outp = nbr + (size_t)row * MAXD;
  int count = 0;
  int dflag = 0;
  const unsigned long long below = (1ull << lane) - 1ull;
  for (int c0 = 0; c0 < NN; c0 += 256) {
    const int c = c0 + lane * 4;
    const f32x4 v = __builtin_nontemporal_load(
        reinterpret_cast<const f32x4*>(arow + c));
    const unsigned long long m0 = __ballot(v[0] > 0.0f);
    const unsigned long long m1 = __ballot(v[1] > 0.0f);
    const unsigned long long m2 = __ballot(v[2] > 0.0f);
    const unsigned long long m3 = __ballot(v[3] > 0.0f);
    int pos = count + (int)(__popcll(m0 & below) + __popcll(m1 & below) +
                            __popcll(m2 & below) + __popcll(m3 & below));
    if (v[0] > 0.0f) { if (pos < MAXD) outp[pos] = c + 0; ++pos; if (c + 0 == row) dflag = 1; }
    if (v[1] > 0.0f) { if (pos < MAXD) outp[pos] = c + 1; ++pos; if (c + 1 == row) dflag = 1; }
    if (v[2] > 0.0f) { if (pos < MAXD) outp[pos] = c + 2; ++pos; if (c + 2 == row) dflag = 1; }
    if (v[3] > 0.0f) { if (pos < MAXD) outp[pos] = c + 3; ++pos; if (c + 3 == row) dflag = 1; }
    count += (int)(__popcll(m0) + __popcll(m1) + __popcll(m2) + __popcll(m3));
  }
  const int anyd = __any(dflag) ? 1 : 0;
  if (lane == 0) {
    deg[row] = count < MAXD ? count : MAXD;
    s2v[row] = count - anyd;
  }
}

// ---------------------------------------------------------------------------
// Kernel B: Wh = h @ W, f32 tiled GEMM (64x64 tile, 4x4 per thread, BK=32).
// ---------------------------------------------------------------------------
__global__ void __launch_bounds__(256) k_gemm(
    const float* __restrict__ A, const float* __restrict__ B,
    float* __restrict__ C) {
  __shared__ float As[32][65];
  __shared__ float Bs[32][65];
  const int tid = threadIdx.x;
  const int brow = blockIdx.y * 64;
  const int bcol = blockIdx.x * 64;
  const int tx = tid & 15;
  const int ty = tid >> 4;
  float acc[4][4];
#pragma unroll
  for (int i = 0; i < 4; ++i)
#pragma unroll
    for (int j = 0; j < 4; ++j) acc[i][j] = 0.0f;
  const int ar = tid >> 2;
  const int ac = (tid & 3) << 2;
  const int br = tid >> 4;
  const int bc = (tid & 15) << 2;
  for (int k0 = 0; k0 < KFIN; k0 += 32) {
    const float4 av0 =
        *reinterpret_cast<const float4*>(A + (size_t)(brow + ar) * KFIN + k0 + ac);
    const float4 av1 =
        *reinterpret_cast<const float4*>(A + (size_t)(brow + ar) * KFIN + k0 + 16 + ac);
    const float4 bv0 =
        *reinterpret_cast<const float4*>(B + (size_t)(k0 + br) * KFOUT + bcol + bc);
    const float4 bv1 =
        *reinterpret_cast<const float4*>(B + (size_t)(k0 + 16 + br) * KFOUT + bcol + bc);
    As[ac + 0][ar] = av0.x;
    As[ac + 1][ar] = av0.y;
    As[ac + 2][ar] = av0.z;
    As[ac + 3][ar] = av0.w;
    As[16 + ac + 0][ar] = av1.x;
    As[16 + ac + 1][ar] = av1.y;
    As[16 + ac + 2][ar] = av1.z;
    As[16 + ac + 3][ar] = av1.w;
    Bs[br][bc + 0] = bv0.x;
    Bs[br][bc + 1] = bv0.y;
    Bs[br][bc + 2] = bv0.z;
    Bs[br][bc + 3] = bv0.w;
    Bs[16 + br][bc + 0] = bv1.x;
    Bs[16 + br][bc + 1] = bv1.y;
    Bs[16 + br][bc + 2] = bv1.z;
    Bs[16 + br][bc + 3] = bv1.w;
    __syncthreads();
#pragma unroll
    for (int kk = 0; kk < 32; ++kk) {
      const float a0 = As[kk][ty * 4 + 0];
      const float a1 = As[kk][ty * 4 + 1];
      const float a2 = As[kk][ty * 4 + 2];
      const float a3 = As[kk][ty * 4 + 3];
      const float b0 = Bs[kk][tx * 4 + 0];
      const float b1 = Bs[kk][tx * 4 + 1];
      const float b2 = Bs[kk][tx * 4 + 2];
      const float b3 = Bs[kk][tx * 4 + 3];
      acc[0][0] += a0 * b0; acc[0][1] += a0 * b1; acc[0][2] += a0 * b2; acc[0][3] += a0 * b3;
      acc[1][0] += a1 * b0; acc[1][1] += a1 * b1; acc[1][2] += a1 * b2; acc[1][3] += a1 * b3;
      acc[2][0] += a2 * b0; acc[2][1] += a2 * b1; acc[2][2] += a2 * b2; acc[2][3] += a2 * b3;
      acc[3][0] += a3 * b0; acc[3][1] += a3 * b1; acc[3][2] += a3 * b2; acc[3][3] += a3 * b3;
    }
    __syncthreads();
  }
#pragma unroll
  for (int i = 0; i < 4; ++i) {
#pragma unroll
    for (int j = 0; j < 4; ++j) {
      C[(size_t)(brow + ty * 4 + i) * KFOUT + bcol + tx * 4 + j] = acc[i][j];
    }
  }
}

// ---------------------------------------------------------------------------
// Kernel C: Wh1/Wh2 row dots, one wave per row (shuffle reduce, no barriers).
// ---------------------------------------------------------------------------
__global__ void __launch_bounds__(256) k_rowdots(
    const float* __restrict__ Wh, const float* __restrict__ a,
    float* __restrict__ Wh1, float* __restrict__ Wh2) {
  const int wave = threadIdx.x >> 6;
  const int lane = threadIdx.x & 63;
  const int row = blockIdx.x * 4 + wave;
  const float4 w = *reinterpret_cast<const float4*>(Wh + (size_t)row * KFOUT + lane * 4);
  const float4 aA = *reinterpret_cast<const float4*>(a + lane * 4);
  const float4 aB = *reinterpret_cast<const float4*>(a + KFOUT + lane * 4);
  float sA = w.x * aA.x + w.y * aA.y + w.z * aA.z + w.w * aA.w;
  float sB = w.x * aB.x + w.y * aB.y + w.z * aB.z + w.w * aB.w;
  for (int o = 32; o > 0; o >>= 1) {
    sA += __shfl_xor(sA, o);
    sB += __shfl_xor(sB, o);
  }
  if (lane == 0) {
    Wh1[row] = sA;
    Wh2[row] = sB;
  }
}

// ---------------------------------------------------------------------------
// Kernel D1: per-row softmax stats (m, Z) + row-normalized attention values
// + octant split counts qb8 + packed mz=(m, 1/Z) -- one edge gather.
// ---------------------------------------------------------------------------
__global__ void __launch_bounds__(256) k_stats(
    const int* __restrict__ nbr, const int* __restrict__ deg,
    const float* __restrict__ Wh1, const float* __restrict__ Wh2,
    float2* __restrict__ mz, float* __restrict__ att,
    short* __restrict__ qb8) {
  const int wave = threadIdx.x >> 6;
  const int lane = threadIdx.x & 63;
  const int row = blockIdx.x * 4 + wave;
  const int d = deg[row];
  const size_t rowbase = (size_t)row * MAXD;
  const int* cols = nbr + rowbase;
  const float w1 = Wh1[row];
  int c0 = 0x7fffffff, c1 = 0x7fffffff, c2 = 0x7fffffff;
  float e0 = -1e30f, e1 = -1e30f, e2 = -1e30f;
  const bool a0 = lane < d, a1 = lane + 64 < d, a2 = lane + 128 < d;
  if (a0) { c0 = cols[lane];       float x = w1 + Wh2[c0]; e0 = x > 0.0f ? x : LRALPHA * x; }
  if (a1) { c1 = cols[lane + 64];  float x = w1 + Wh2[c1]; e1 = x > 0.0f ? x : LRALPHA * x; }
  if (a2) { c2 = cols[lane + 128]; float x = w1 + Wh2[c2]; e2 = x > 0.0f ? x : LRALPHA * x; }
  float mx = fmaxf(e0, fmaxf(e1, e2));
  for (int o = 32; o > 0; o >>= 1) mx = fmaxf(mx, __shfl_xor(mx, o));
  const float x0 = a0 ? expf(e0 - mx) : 0.0f;
  const float x1 = a1 ? expf(e1 - mx) : 0.0f;
  const float x2 = a2 ? expf(e2 - mx) : 0.0f;
  float sum = x0 + x1 + x2;
  for (int o = 32; o > 0; o >>= 1) sum += __shfl_xor(sum, o);
  const float Z = (d > 0) ? sum : 1.0f;
  const float invZ = 1.0f / Z;
  if (a0) att[rowbase + lane] = x0 * invZ;
  if (a1) att[rowbase + lane + 64] = x1 * invZ;
  if (a2) att[rowbase + lane + 128] = x2 * invZ;
  int b[7] = {0, 0, 0, 0, 0, 0, 0};
#pragma unroll
  for (int m = 1; m <= 7; ++m) {
    b[m - 1] = (int)__popcll(__ballot(a0 && c0 < m * 1024)) +
               (int)__popcll(__ballot(a1 && c1 < m * 1024)) +
               (int)__popcll(__ballot(a2 && c2 < m * 1024));
  }
  if (lane == 0) {
    mz[row] = make_float2(mx, invZ);
    short* q = qb8 + (size_t)row * 8;
    q[0] = (short)b[0]; q[1] = (short)b[1]; q[2] = (short)b[2]; q[3] = (short)b[3];
    q[4] = (short)b[4]; q[5] = (short)b[5]; q[6] = (short)b[6]; q[7] = (short)d;
  }
}

// ---------------------------------------------------------------------------
// Kernel D2: packed transpose-edge values (uses packed mz: 2 gathers + mul).
// ---------------------------------------------------------------------------
__global__ void __launch_bounds__(256) k_att(
    const int* __restrict__ nbr, const int* __restrict__ deg,
    const float* __restrict__ Wh1, const float* __restrict__ Wh2,
    const float2* __restrict__ mz, int2* __restrict__ edgesT) {
  const int wave = threadIdx.x >> 6;
  const int lane = threadIdx.x & 63;
  const int row = blockIdx.x * 4 + wave;
  const int d = deg[row];
  const size_t rowbase = (size_t)row * MAXD;
  const int* cols = nbr + rowbase;
  const float w2r = Wh2[row];
  for (int t = lane; t < d; t += 64) {
    const int j = cols[t];
    float e2 = Wh1[j] + w2r;
    e2 = e2 > 0.0f ? e2 : LRALPHA * e2;
    const float2 m = mz[j];
    const float v = expf(e2 - m.x) * m.y;
    edgesT[rowbase + t] = make_int2(j, __float_as_int(v));
  }
}

// ---------------------------------------------------------------------------
// Kernel E: per row i, 512 threads (8 waves). FUSED: two-step prune + h_prime.
// - stage cols/att/sqb; each thread computes its h_prime partial in a
//   register (c = tid&255, parity-split neighbors) -- hides in scatter slack.
// - R6 scatter (octant-partitioned 8-lane groups, LDS atomics, wave-exclusive
//   octants -> replay-deterministic).
// - h_prime partials parked into the dead sqb buffer after the scatter sync.
// - select: dense 8-bit pass 0 -> compact candidates -> passes 1-3 on the
//   compact array (dense fallback nc>512).
// - out1 binary row + out0 = elu(h_prime) epilogue, nt stores.
// ---------------------------------------------------------------------------
__global__ void __launch_bounds__(512) k_twostep(
    const int* __restrict__ nbr, const int* __restrict__ deg,
    const int* __restrict__ s2v, const float* __restrict__ att,
    const int2* __restrict__ edgesT, const short* __restrict__ qb8,
    const float* __restrict__ Wh, float* __restrict__ out1,
    float* __restrict__ out0) {
  __shared__ float comb[NN];                 // 32768 B
  __shared__ float wvals[MAXD];              //   768 B
  __shared__ unsigned short kcols[MAXD];     //   384 B
  __shared__ short sqb[MAXD][8];             //  3072 B (reused as hp[512])
  __shared__ unsigned int hist[256];         //  1024 B
  __shared__ unsigned int scomp[512];        //  2048 B
  __shared__ unsigned int shPrefix;
  __shared__ int shRemaining;
  __shared__ int shNc;
  const int tid = threadIdx.x;
  const int wave = tid >> 6;
  const int lane = tid & 63;
  const int row = blockIdx.x;
  const f32x4 z4 = {0.0f, 0.0f, 0.0f, 0.0f};
  for (int j = tid * 4; j < NN; j += 2048)
    *reinterpret_cast<f32x4*>(&comb[j]) = z4;
  const int d = deg[row];
  const int* cols = nbr + (size_t)row * MAXD;
  const float* arow = att + (size_t)row * MAXD;
  for (int t = tid; t < d; t += 512) {
    const int c = cols[t];
    kcols[t] = (unsigned short)c;
    wvals[t] = arow[t];
    *reinterpret_cast<int4*>(&sqb[t][0]) =
        *reinterpret_cast<const int4*>(&qb8[(size_t)c * 8]);
  }
  if (tid == 0) shNc = 0;
  __syncthreads();
  // --- h_prime partial in register: c = tid&255, neighbors t = parity(tid>>8)
  float hpacc;
  {
    const int c = tid & 255;
    const int half = tid >> 8;
    float p0 = 0.0f, p1 = 0.0f, p2 = 0.0f, p3 = 0.0f;
    int t = half;
    for (; t + 6 < d; t += 8) {
      p0 += wvals[t]     * Wh[(size_t)kcols[t]     * KFOUT + c];
      p1 += wvals[t + 2] * Wh[(size_t)kcols[t + 2] * KFOUT + c];
      p2 += wvals[t + 4] * Wh[(size_t)kcols[t + 4] * KFOUT + c];
      p3 += wvals[t + 6] * Wh[(size_t)kcols[t + 6] * KFOUT + c];
    }
    for (; t < d; t += 2) p0 += wvals[t] * Wh[(size_t)kcols[t] * KFOUT + c];
    hpacc = (p0 + p1) + (p2 + p3);
  }
  // --- group-expanded scatter: 8 groups x 8 lanes per wave (R6 form)
  {
    const int grp = lane >> 3;   // 0..7: which neighbor within the batch
    const int sub = lane & 7;    // 0..7: offset within the segment
    for (int t0 = 0; t0 < d; t0 += 8) {
      const int t = t0 + grp;
      if (t < d) {
        const int qs = wave ? (int)sqb[t][wave - 1] : 0;
        const int qe = (int)sqb[t][wave];
        const float w = wvals[t];
        const int2* ek = edgesT + (size_t)kcols[t] * MAXD;
        for (int off = qs + sub; off < qe; off += 8) {
          const int2 e = ek[off];
          atomicAdd(&comb[e.x], w * __int_as_float(e.y));
        }
      }
    }
  }
  // --- add row's own attention values (wave's own octant segment)
  {
    const short* qr = qb8 + (size_t)row * 8;
    const int qlo = wave ? (int)qr[wave - 1] : 0;
    const int qhi = (int)qr[wave];
    for (int t = qlo + lane; t < qhi; t += 64) comb[(int)kcols[t]] += wvals[t];
  }
  __syncthreads();
  // sqb is dead now: park h_prime partials there; zero the diagonal.
  float* hp = reinterpret_cast<float*>(&sqb[0][0]);
  hp[tid] = hpacc;
  if (tid == 0) comb[row] = 0.0f;
  __syncthreads();
  const int kk = s2v[row];
  const size_t obase = (size_t)row * NN;
  if (kk <= 0) {
    for (int j = tid * 4; j < NN; j += 2048)
      __builtin_nontemporal_store(z4, reinterpret_cast<f32x4*>(&out1[obase + j]));
  } else {
    // --- pass 0: dense 8-bit radix over comb (zeros skipped; threshold > 0)
    if (tid < 256) hist[tid] = 0u;
    __syncthreads();
    for (int j = tid * 4; j < NN; j += 2048) {
      const f32x4 cv = *reinterpret_cast<const f32x4*>(&comb[j]);
#pragma unroll
      for (int q = 0; q < 4; ++q) {
        const unsigned int u = __float_as_uint(cv[q]);
        if (u != 0u) atomicAdd(&hist[u >> 24], 1u);
      }
    }
    __syncthreads();
    if (tid < 64) {
      const int bHi = 255 - 4 * lane;  // lane 0 owns highest bins
      const unsigned int c0 = hist[bHi];
      const unsigned int c1 = hist[bHi - 1];
      const unsigned int c2 = hist[bHi - 2];
      const unsigned int c3 = hist[bHi - 3];
      const unsigned int gs = c0 + c1 + c2 + c3;
      unsigned int run2 = gs;
      for (int o = 1; o < 64; o <<= 1) {
        const unsigned int tt = __shfl_up(run2, o);
        if (lane >= o) run2 += tt;
      }
      const unsigned int pre = run2 - gs;
      const unsigned int rem = (unsigned int)kk;
      if (pre < rem && pre + gs >= rem) {
        unsigned int above;
        int digit;
        if (pre + c0 >= rem) { digit = bHi; above = pre; }
        else if (pre + c0 + c1 >= rem) { digit = bHi - 1; above = pre + c0; }
        else if (pre + c0 + c1 + c2 >= rem) { digit = bHi - 2; above = pre + c0 + c1; }
        else { digit = bHi - 3; above = pre + c0 + c1 + c2; }
        shPrefix = (unsigned)digit << 24;
        shRemaining = kk - (int)above;
      }
    }
    __syncthreads();
    unsigned int prefix = shPrefix;
    int remaining = shRemaining;
    const unsigned int digit0 = prefix >> 24;
    __syncthreads();
    // --- compact the chosen bin's candidates (order-independent multiset)
    for (int j = tid * 4; j < NN; j += 2048) {
      const f32x4 cv = *reinterpret_cast<const f32x4*>(&comb[j]);
#pragma unroll
      for (int q = 0; q < 4; ++q) {
        const unsigned int u = __float_as_uint(cv[q]);
        if (u != 0u && (u >> 24) == digit0) {
          const int idx = atomicAdd(&shNc, 1);
          if (idx < 512) scomp[idx] = u;
        }
      }
    }
    __syncthreads();
    const int nc = shNc;
    const bool densefb = nc > 512;  // rare fallback
    const unsigned int myu = (!densefb && tid < nc) ? scomp[tid] : 0u;
    for (int pass = 1; pass < 4; ++pass) {
      const int shift = 24 - 8 * pass;
      const unsigned int pmask = 0xFFFFFFFFu << (shift + 8);
      if (tid < 256) hist[tid] = 0u;
      __syncthreads();
      if (!densefb) {
        if (tid < nc && (myu & pmask) == prefix)
          atomicAdd(&hist[(myu >> shift) & 255u], 1u);
      } else {
        for (int j = tid * 4; j < NN; j += 2048) {
          const f32x4 cv = *reinterpret_cast<const f32x4*>(&comb[j]);
#pragma unroll
          for (int q = 0; q < 4; ++q) {
            const unsigned int u = __float_as_uint(cv[q]);
            if (u != 0u && (u & pmask) == prefix)
              atomicAdd(&hist[(u >> shift) & 255u], 1u);
          }
        }
      }
      __syncthreads();
      if (tid < 64) {
        const int bHi = 255 - 4 * lane;
        const unsigned int c0 = hist[bHi];
        const unsigned int c1 = hist[bHi - 1];
        const unsigned int c2 = hist[bHi - 2];
        const unsigned int c3 = hist[bHi - 3];
        const unsigned int gs = c0 + c1 + c2 + c3;
        unsigned int run2 = gs;
        for (int o = 1; o < 64; o <<= 1) {
          const unsigned int tt = __shfl_up(run2, o);
          if (lane >= o) run2 += tt;
        }
        const unsigned int pre = run2 - gs;
        const unsigned int rem = (unsigned int)remaining;
        if (pre < rem && pre + gs >= rem) {
          unsigned int above;
          int digit;
          if (pre + c0 >= rem) { digit = bHi; above = pre; }
          else if (pre + c0 + c1 >= rem) { digit = bHi - 1; above = pre + c0; }
          else if (pre + c0 + c1 + c2 >= rem) { digit = bHi - 2; above = pre + c0 + c1; }
          else { digit = bHi - 3; above = pre + c0 + c1 + c2; }
          shPrefix = prefix | ((unsigned int)digit << shift);
          shRemaining = remaining - (int)above;
        }
      }
      __syncthreads();
      prefix = shPrefix;
      remaining = shRemaining;
      __syncthreads();
    }
    const float thr = __uint_as_float(prefix);  // exact kk-th largest value
    for (int j = tid * 4; j < NN; j += 2048) {
      const f32x4 cv = *reinterpret_cast<const f32x4*>(&comb[j]);
      f32x4 ov;
      ov[0] = (cv[0] >= thr && cv[0] > 0.0f) ? 1.0f : 0.0f;
      ov[1] = (cv[1] >= thr && cv[1] > 0.0f) ? 1.0f : 0.0f;
      ov[2] = (cv[2] >= thr && cv[2] > 0.0f) ? 1.0f : 0.0f;
      ov[3] = (cv[3] >= thr && cv[3] > 0.0f) ? 1.0f : 0.0f;
      __builtin_nontemporal_store(ov, reinterpret_cast<f32x4*>(&out1[obase + j]));
    }
  }
  // --- out0 epilogue: combine the two parity partials, ELU, nt store
  if (tid < 256) {
    const float acc = hp[tid] + hp[tid + 256];
    const float r = acc > 0.0f ? acc : expm1f(acc);
    __builtin_nontemporal_store(r, &out0[(size_t)row * KFOUT + tid]);
  }
}

extern "C" void kernel_launch(void* const* d_in, const int* in_sizes, int n_in,
                              void* d_out, int out_size, void* d_ws, size_t ws_size,
                              hipStream_t stream) {
  const float* h = (const float*)d_in[0];
  const float* adj = (const float*)d_in[1];
  const float* W = (const float*)d_in[2];
  const float* a = (const float*)d_in[3];

  float* out0 = (float*)d_out;                  // [8192, 256] elu(h_prime)
  float* out1 = out0 + (size_t)NN * KFOUT;      // [8192, 8192] adj_resize

  // workspace layout (~34 MB)
  float* Wh = (float*)d_ws;                        // 8192*256
  float* Wh1 = Wh + (size_t)NN * KFOUT;            // 8192
  float* Wh2 = Wh1 + NN;                           // 8192
  float* mrow = Wh2 + NN;                          // 8192 (unused legacy slot)
  float* Zrow = mrow + NN;                         // 8192 (unused legacy slot)
  float* att = Zrow + NN;                          // 8192*MAXD
  float* edgesF = att + (size_t)NN * MAXD;         // 8192*MAXD int2
  int2* edgesT = (int2*)edgesF;
  int* nbr = (int*)(edgesF + (size_t)NN * MAXD * 2);  // 8192*MAXD
  int* deg = nbr + (size_t)NN * MAXD;              // 8192
  int* s2v = deg + NN;                             // 8192
  short* qb8 = (short*)(s2v + NN);                 // 8192*8 shorts (128 KB)
  float2* mz = (float2*)(qb8 + (size_t)NN * 8);    // 8192 float2 (64 KB)

  k_build_csr<<<NN / 4, 256, 0, stream>>>(adj, nbr, deg, s2v);
  dim3 ggrid(KFOUT / 64, NN / 64);
  k_gemm<<<ggrid, 256, 0, stream>>>(h, W, Wh);
  k_rowdots<<<NN / 4, 256, 0, stream>>>(Wh, a, Wh1, Wh2);
  k_stats<<<NN / 4, 256, 0, stream>>>(nbr, deg, Wh1, Wh2, mz, att, qb8);
  k_att<<<NN / 4, 256, 0, stream>>>(nbr, deg, Wh1, Wh2, mz, edgesT);
  k_twostep<<<NN, 512, 0, stream>>>(nbr, deg, s2v, att, edgesT, qb8, Wh,
                                    out1, out0);
}